// Round 1
// baseline (1029.654 us; speedup 1.0000x reference)
//
#include <hip/hip_runtime.h>
#include <stdint.h>
#include <stddef.h>

// Problem geometry (fixed by setup_inputs)
static constexpr int    M_ROWS = 8192;   // B*K
static constexpr int    DMODEL = 256;
static constexpr int    BDIM   = 2700;
static constexpr int    NCODES = 1024;
static constexpr size_t QST_N  = (size_t)M_ROWS * (size_t)BDIM;  // 22118400

// ---------------------------------------------------------------------------
// Tiled fp32 NT-GEMM: C[m,n] = sum_k A[m,k]*B[n,k]  (+ epilogue)
// MODE 0: C = A*B^T + bias[n]              (z_e projection)
// MODE 1: C = rsq[m] - 2*(A*B^T) + csq[n]  (squared euclidean distances)
// 128x128 block tile, BK=16, 256 threads, 8x8 microtile, double-buffered LDS.
// ---------------------------------------------------------------------------
template<int MODE>
__global__ __launch_bounds__(256, 2)
void gemm_nt(const float* __restrict__ A, const float* __restrict__ B,
             const float* __restrict__ bias,
             const float* __restrict__ rsq, const float* __restrict__ csq,
             float* __restrict__ C, int Ndim, int Kdim, int lda, int ldb, int ldc)
{
    constexpr int BK = 16;
    constexpr int LS = 132;   // BM + 4 pad: 16B-aligned rows, conflict-light
    __shared__ float As[2][BK][LS];
    __shared__ float Bs[2][BK][LS];

    const int tid  = threadIdx.x;
    const int row0 = blockIdx.y << 7;
    const int col0 = blockIdx.x << 7;

    // staging coords: each thread loads float4 along K for one row, twice (half)
    const int sm = tid >> 2;          // 0..63
    const int sk = (tid & 3) << 2;    // 0,4,8,12

    // compute coords: 4 waves in 2x2 quadrants; 8x8 lanes; 8x8 micro each
    const int wid  = tid >> 6;
    const int lane = tid & 63;
    const int tr = ((wid >> 1) << 6) | ((lane >> 3) << 3);
    const int tc = ((wid & 1) << 6) | ((lane & 7) << 3);

    float acc[8][8];
#pragma unroll
    for (int i = 0; i < 8; ++i)
#pragma unroll
        for (int j = 0; j < 8; ++j) acc[i][j] = 0.0f;

    const int nt = (Kdim + BK - 1) / BK;

    auto stage = [&](int t, int buf) {
        const int  kt    = t * BK;
        const bool kfull = (kt + BK) <= Kdim;
#pragma unroll
        for (int half = 0; half < 2; ++half) {
            const int m = sm + (half << 6);
            {   // A tile row (M = 8192, always in-bounds for our grids)
                const long long gr = row0 + m;
                const float* ap = A + gr * (long long)lda + kt + sk;
                float4 v;
                if (kfull) {
                    v = *reinterpret_cast<const float4*>(ap);
                } else {
                    v.x = (kt + sk + 0 < Kdim) ? ap[0] : 0.0f;
                    v.y = (kt + sk + 1 < Kdim) ? ap[1] : 0.0f;
                    v.z = (kt + sk + 2 < Kdim) ? ap[2] : 0.0f;
                    v.w = (kt + sk + 3 < Kdim) ? ap[3] : 0.0f;
                }
                As[buf][sk + 0][m] = v.x; As[buf][sk + 1][m] = v.y;
                As[buf][sk + 2][m] = v.z; As[buf][sk + 3][m] = v.w;
            }
            {   // B tile row (guard n < Ndim for the 2700 tail)
                const long long gc = col0 + m;
                float4 v; v.x = v.y = v.z = v.w = 0.0f;
                if (gc < Ndim) {
                    const float* bp = B + gc * (long long)ldb + kt + sk;
                    if (kfull) {
                        v = *reinterpret_cast<const float4*>(bp);
                    } else {
                        v.x = (kt + sk + 0 < Kdim) ? bp[0] : 0.0f;
                        v.y = (kt + sk + 1 < Kdim) ? bp[1] : 0.0f;
                        v.z = (kt + sk + 2 < Kdim) ? bp[2] : 0.0f;
                        v.w = (kt + sk + 3 < Kdim) ? bp[3] : 0.0f;
                    }
                }
                Bs[buf][sk + 0][m] = v.x; Bs[buf][sk + 1][m] = v.y;
                Bs[buf][sk + 2][m] = v.z; Bs[buf][sk + 3][m] = v.w;
            }
        }
    };

    stage(0, 0);
    __syncthreads();
    for (int t = 0; t < nt; ++t) {
        const int buf = t & 1;
        if (t + 1 < nt) stage(t + 1, buf ^ 1);
#pragma unroll
        for (int kk = 0; kk < BK; ++kk) {
            const float4 a0 = *reinterpret_cast<const float4*>(&As[buf][kk][tr]);
            const float4 a1 = *reinterpret_cast<const float4*>(&As[buf][kk][tr + 4]);
            const float4 b0 = *reinterpret_cast<const float4*>(&Bs[buf][kk][tc]);
            const float4 b1 = *reinterpret_cast<const float4*>(&Bs[buf][kk][tc + 4]);
            const float av[8] = {a0.x, a0.y, a0.z, a0.w, a1.x, a1.y, a1.z, a1.w};
            const float bv[8] = {b0.x, b0.y, b0.z, b0.w, b1.x, b1.y, b1.z, b1.w};
#pragma unroll
            for (int i = 0; i < 8; ++i)
#pragma unroll
                for (int j = 0; j < 8; ++j)
                    acc[i][j] = __builtin_fmaf(av[i], bv[j], acc[i][j]);
        }
        __syncthreads();
    }

#pragma unroll
    for (int i = 0; i < 8; ++i) {
        const long long gr = row0 + tr + i;
        float* crow = C + gr * (long long)ldc;
        float zr = 0.0f;
        if constexpr (MODE == 1) zr = rsq[gr];
#pragma unroll
        for (int jj = 0; jj < 8; jj += 4) {
            const int gc = col0 + tc + jj;
            if (gc + 4 <= Ndim) {   // Ndim % 4 == 0 so f4 is all-or-nothing
                float4 o;
                if constexpr (MODE == 0) {
                    const float4 bb = *reinterpret_cast<const float4*>(bias + gc);
                    o.x = acc[i][jj + 0] + bb.x;
                    o.y = acc[i][jj + 1] + bb.y;
                    o.z = acc[i][jj + 2] + bb.z;
                    o.w = acc[i][jj + 3] + bb.w;
                } else {
                    const float4 ee = *reinterpret_cast<const float4*>(csq + gc);
                    o.x = zr - 2.0f * acc[i][jj + 0] + ee.x;
                    o.y = zr - 2.0f * acc[i][jj + 1] + ee.y;
                    o.z = zr - 2.0f * acc[i][jj + 2] + ee.z;
                    o.w = zr - 2.0f * acc[i][jj + 3] + ee.w;
                }
                *reinterpret_cast<float4*>(crow + gc) = o;
            }
        }
    }
}

// ---------------------------------------------------------------------------
// Row-wise sum of squares (used for ||e||^2 over embed and ||z||^2 over z_e)
// ---------------------------------------------------------------------------
__global__ __launch_bounds__(256)
void rowsumsq(const float* __restrict__ src, float* __restrict__ out, int ncols)
{
    const int row = blockIdx.x;
    const float4* s = reinterpret_cast<const float4*>(src + (size_t)row * ncols);
    const int n4 = ncols >> 2;
    float acc = 0.0f;
    for (int i = threadIdx.x; i < n4; i += 256) {
        const float4 v = s[i];
        acc += v.x * v.x + v.y * v.y + v.z * v.z + v.w * v.w;
    }
    for (int off = 32; off; off >>= 1) acc += __shfl_down(acc, off);
    __shared__ float wsum[4];
    if ((threadIdx.x & 63) == 0) wsum[threadIdx.x >> 6] = acc;
    __syncthreads();
    if (threadIdx.x == 0) out[row] = wsum[0] + wsum[1] + wsum[2] + wsum[3];
}

// ---------------------------------------------------------------------------
// Per-row: argmin (numpy first-min tie-break), softmax sum, avg_prob atomics,
// index outputs, and sum of min-dist (== sum of ||z - e_idx||^2) for vq_loss.
// ---------------------------------------------------------------------------
__global__ __launch_bounds__(256)
void row_softmax(const float* __restrict__ dist, float* __restrict__ prob_acc,
                 float* __restrict__ sse, float* __restrict__ out_idx_f,
                 int* __restrict__ out_idx_i)
{
    const int row = blockIdx.x;
    const int tid = threadIdx.x;
    const float4 d4 = reinterpret_cast<const float4*>(dist + (size_t)row * NCODES)[tid];
    const float dv[4] = {d4.x, d4.y, d4.z, d4.w};

    // monotonic float->uint key (handles any sign safely)
    unsigned long long best;
    {
        unsigned u0 = __float_as_uint(dv[0]);
        unsigned k0 = (u0 & 0x80000000u) ? ~u0 : (u0 | 0x80000000u);
        best = ((unsigned long long)k0 << 32) | (unsigned)(tid * 4 + 0);
#pragma unroll
        for (int j = 1; j < 4; ++j) {
            unsigned u = __float_as_uint(dv[j]);
            unsigned k = (u & 0x80000000u) ? ~u : (u | 0x80000000u);
            unsigned long long cand = ((unsigned long long)k << 32) | (unsigned)(tid * 4 + j);
            if (cand < best) best = cand;
        }
    }
    for (int off = 32; off; off >>= 1) {
        unsigned long long o = __shfl_down(best, off);
        if (o < best) best = o;
    }
    __shared__ unsigned long long wmin[4];
    __shared__ float wred[4];
    if ((tid & 63) == 0) wmin[tid >> 6] = best;
    __syncthreads();
    unsigned long long b4 = wmin[0];
    if (wmin[1] < b4) b4 = wmin[1];
    if (wmin[2] < b4) b4 = wmin[2];
    if (wmin[3] < b4) b4 = wmin[3];
    const unsigned ku = (unsigned)(b4 >> 32);
    const float m = (ku & 0x80000000u) ? __uint_as_float(ku & 0x7fffffffu)
                                       : __uint_as_float(~ku);
    const int idx = (int)(b4 & 0xffffffffu);

    // softmax(-dist): exp(m - d) / S
    float e[4];
    float s_local = 0.0f;
#pragma unroll
    for (int j = 0; j < 4; ++j) { e[j] = expf(m - dv[j]); s_local += e[j]; }
    for (int off = 32; off; off >>= 1) s_local += __shfl_down(s_local, off);
    if ((tid & 63) == 0) wred[tid >> 6] = s_local;
    __syncthreads();
    const float S = wred[0] + wred[1] + wred[2] + wred[3];
    const float scale = (1.0f / S) * 0.0001220703125f;  // /S /8192
#pragma unroll
    for (int j = 0; j < 4; ++j)
        if (e[j] > 0.0f) atomicAdd(&prob_acc[tid * 4 + j], e[j] * scale);

    if (tid == 0) {
        out_idx_f[row] = (float)idx;
        out_idx_i[row] = idx;
        atomicAdd(sse, m);
    }
}

// ---------------------------------------------------------------------------
// q_st[n,:] = embed[idx[n],:]   (straight-through forward value)
// ---------------------------------------------------------------------------
__global__ __launch_bounds__(256)
void gather_q(const float* __restrict__ embed, const int* __restrict__ idx,
              float* __restrict__ q)
{
    const int row  = blockIdx.x;
    const int code = idx[row];
    const float4* s = reinterpret_cast<const float4*>(embed + (size_t)code * BDIM);
    float4*       d = reinterpret_cast<float4*>(q + (size_t)row * BDIM);
    for (int i = threadIdx.x; i < (BDIM >> 2); i += 256) d[i] = s[i];
}

__global__ void init_ws(float* __restrict__ prob_acc, float* __restrict__ sse)
{
    const int t = threadIdx.x;
    if (t < NCODES) prob_acc[t] = 0.0f;
    if (t == 0) sse[0] = 0.0f;
}

__global__ __launch_bounds__(256)
void finalize(const float* __restrict__ prob_acc, const float* __restrict__ sse,
              float* __restrict__ out)
{
    const int tid = threadIdx.x;
    float ent = 0.0f;
    for (int c = tid; c < NCODES; c += 256) {
        const float a = prob_acc[c];                 // already mean over rows
        ent -= a * logf(a + 1e-8f);
    }
    for (int off = 32; off; off >>= 1) ent += __shfl_down(ent, off);
    __shared__ float wred[4];
    if ((tid & 63) == 0) wred[tid >> 6] = ent;
    __syncthreads();
    if (tid == 0) {
        out[QST_N + M_ROWS + 0] = sse[0] / 22118400.0f;            // vq_loss
        out[QST_N + M_ROWS + 1] = wred[0] + wred[1] + wred[2] + wred[3]; // entropy
    }
}

extern "C" void kernel_launch(void* const* d_in, const int* in_sizes, int n_in,
                              void* d_out, int out_size, void* d_ws, size_t ws_size,
                              hipStream_t stream)
{
    (void)in_sizes; (void)n_in; (void)out_size; (void)ws_size;
    const float* slot = (const float*)d_in[0];
    const float* W    = (const float*)d_in[1];
    const float* bpr  = (const float*)d_in[2];
    const float* emb  = (const float*)d_in[3];

    float* out  = (float*)d_out;
    float* Z    = out;              // z_e lives in the q_st region, overwritten by gather
    float* idxf = out + QST_N;

    // workspace layout (needs ~33.7 MB)
    float* dist = (float*)d_ws;
    float* zsq  = dist + (size_t)M_ROWS * NCODES;
    float* esq  = zsq + M_ROWS;
    int*   idxi = (int*)(esq + NCODES);
    float* prob = (float*)(idxi + M_ROWS);
    float* sse  = prob + NCODES;

    init_ws<<<1, 1024, 0, stream>>>(prob, sse);
    rowsumsq<<<NCODES, 256, 0, stream>>>(emb, esq, BDIM);
    gemm_nt<0><<<dim3((BDIM + 127) / 128, M_ROWS / 128), 256, 0, stream>>>(
        slot, W, bpr, nullptr, nullptr, Z, BDIM, DMODEL, DMODEL, DMODEL, BDIM);
    rowsumsq<<<M_ROWS, 256, 0, stream>>>(Z, zsq, BDIM);
    gemm_nt<1><<<dim3(NCODES / 128, M_ROWS / 128), 256, 0, stream>>>(
        Z, emb, nullptr, zsq, esq, dist, NCODES, BDIM, BDIM, BDIM, NCODES);
    row_softmax<<<M_ROWS, 256, 0, stream>>>(dist, prob, sse, idxf, idxi);
    gather_q<<<M_ROWS, 256, 0, stream>>>(emb, idxi, Z);
    finalize<<<1, 256, 0, stream>>>(prob, sse, out);
}

// Round 3
// 1016.367 us; speedup vs baseline: 1.0131x; 1.0131x over previous
//
#include <hip/hip_runtime.h>
#include <stdint.h>
#include <stddef.h>

// Problem geometry (fixed by setup_inputs)
static constexpr int    M_ROWS = 8192;   // B*K
static constexpr int    DMODEL = 256;
static constexpr int    BDIM   = 2700;
static constexpr int    NCODES = 1024;
static constexpr int    KP     = 2720;   // BDIM padded to multiple of 32 (85 K-steps)
static constexpr size_t QST_N  = (size_t)M_ROWS * (size_t)BDIM;  // 22118400

typedef __bf16 bf16x8 __attribute__((ext_vector_type(8)));
typedef float  f32x4  __attribute__((ext_vector_type(4)));

// ---------------------------------------------------------------------------
// helpers: fp32 -> bf16 split (RNE), argmin key packing
// ---------------------------------------------------------------------------
__device__ inline unsigned short bf16h(float x) {
    unsigned u = __float_as_uint(x);
    unsigned r = u + 0x7fffu + ((u >> 16) & 1u);
    return (unsigned short)(r >> 16);
}
__device__ inline void split2(float x, unsigned short& h, unsigned short& l) {
    h = bf16h(x);
    const float hf = __uint_as_float(((unsigned)h) << 16);
    l = bf16h(x - hf);
}
__device__ inline unsigned long long pack_key(float v, int idx) {
    unsigned u = __float_as_uint(v);
    unsigned k = (u & 0x80000000u) ? ~u : (u | 0x80000000u);
    return ((unsigned long long)k << 32) | (unsigned)idx;
}
__device__ inline float unpack_val(unsigned long long key) {
    unsigned ku = (unsigned)(key >> 32);
    return (ku & 0x80000000u) ? __uint_as_float(ku & 0x7fffffffu)
                              : __uint_as_float(~ku);
}

// ---------------------------------------------------------------------------
// Tiled fp32 NT-GEMM: MODE 0 writes z (+ optional bf16 hi/lo splits),
// MODE 1 is the fp32 fallback distance GEMM.
// ---------------------------------------------------------------------------
template<int MODE>
__global__ __launch_bounds__(256, 2)
void gemm_nt(const float* __restrict__ A, const float* __restrict__ B,
             const float* __restrict__ bias,
             const float* __restrict__ rsq, const float* __restrict__ csq,
             float* __restrict__ C, int Ndim, int Kdim, int lda, int ldb, int ldc,
             unsigned short* __restrict__ zhi, unsigned short* __restrict__ zlo)
{
    constexpr int BK = 16;
    constexpr int LS = 132;
    __shared__ float As[2][BK][LS];
    __shared__ float Bs[2][BK][LS];

    const int tid  = threadIdx.x;
    const int row0 = blockIdx.y << 7;
    const int col0 = blockIdx.x << 7;

    const int sm = tid >> 2;
    const int sk = (tid & 3) << 2;

    const int wid  = tid >> 6;
    const int lane = tid & 63;
    const int tr = ((wid >> 1) << 6) | ((lane >> 3) << 3);
    const int tc = ((wid & 1) << 6) | ((lane & 7) << 3);

    float acc[8][8];
#pragma unroll
    for (int i = 0; i < 8; ++i)
#pragma unroll
        for (int j = 0; j < 8; ++j) acc[i][j] = 0.0f;

    const int nt = (Kdim + BK - 1) / BK;

    auto stage = [&](int t, int buf) {
        const int  kt    = t * BK;
        const bool kfull = (kt + BK) <= Kdim;
#pragma unroll
        for (int half = 0; half < 2; ++half) {
            const int m = sm + (half << 6);
            {
                const long long gr = row0 + m;
                const float* ap = A + gr * (long long)lda + kt + sk;
                float4 v;
                if (kfull) {
                    v = *reinterpret_cast<const float4*>(ap);
                } else {
                    v.x = (kt + sk + 0 < Kdim) ? ap[0] : 0.0f;
                    v.y = (kt + sk + 1 < Kdim) ? ap[1] : 0.0f;
                    v.z = (kt + sk + 2 < Kdim) ? ap[2] : 0.0f;
                    v.w = (kt + sk + 3 < Kdim) ? ap[3] : 0.0f;
                }
                As[buf][sk + 0][m] = v.x; As[buf][sk + 1][m] = v.y;
                As[buf][sk + 2][m] = v.z; As[buf][sk + 3][m] = v.w;
            }
            {
                const long long gc = col0 + m;
                float4 v; v.x = v.y = v.z = v.w = 0.0f;
                if (gc < Ndim) {
                    const float* bp = B + gc * (long long)ldb + kt + sk;
                    if (kfull) {
                        v = *reinterpret_cast<const float4*>(bp);
                    } else {
                        v.x = (kt + sk + 0 < Kdim) ? bp[0] : 0.0f;
                        v.y = (kt + sk + 1 < Kdim) ? bp[1] : 0.0f;
                        v.z = (kt + sk + 2 < Kdim) ? bp[2] : 0.0f;
                        v.w = (kt + sk + 3 < Kdim) ? bp[3] : 0.0f;
                    }
                }
                Bs[buf][sk + 0][m] = v.x; Bs[buf][sk + 1][m] = v.y;
                Bs[buf][sk + 2][m] = v.z; Bs[buf][sk + 3][m] = v.w;
            }
        }
    };

    stage(0, 0);
    __syncthreads();
    for (int t = 0; t < nt; ++t) {
        const int buf = t & 1;
        if (t + 1 < nt) stage(t + 1, buf ^ 1);
#pragma unroll
        for (int kk = 0; kk < BK; ++kk) {
            const float4 a0 = *reinterpret_cast<const float4*>(&As[buf][kk][tr]);
            const float4 a1 = *reinterpret_cast<const float4*>(&As[buf][kk][tr + 4]);
            const float4 b0 = *reinterpret_cast<const float4*>(&Bs[buf][kk][tc]);
            const float4 b1 = *reinterpret_cast<const float4*>(&Bs[buf][kk][tc + 4]);
            const float av[8] = {a0.x, a0.y, a0.z, a0.w, a1.x, a1.y, a1.z, a1.w};
            const float bv[8] = {b0.x, b0.y, b0.z, b0.w, b1.x, b1.y, b1.z, b1.w};
#pragma unroll
            for (int i = 0; i < 8; ++i)
#pragma unroll
                for (int j = 0; j < 8; ++j)
                    acc[i][j] = __builtin_fmaf(av[i], bv[j], acc[i][j]);
        }
        __syncthreads();
    }

#pragma unroll
    for (int i = 0; i < 8; ++i) {
        const long long gr = row0 + tr + i;
        float* crow = C + gr * (long long)ldc;
        float zr = 0.0f;
        if constexpr (MODE == 1) zr = rsq[gr];
#pragma unroll
        for (int jj = 0; jj < 8; jj += 4) {
            const int gc = col0 + tc + jj;
            if (gc + 4 <= Ndim) {
                float4 o;
                if constexpr (MODE == 0) {
                    const float4 bb = *reinterpret_cast<const float4*>(bias + gc);
                    o.x = acc[i][jj + 0] + bb.x;
                    o.y = acc[i][jj + 1] + bb.y;
                    o.z = acc[i][jj + 2] + bb.z;
                    o.w = acc[i][jj + 3] + bb.w;
                    if (zhi) {   // bf16 split-2 of z for the MFMA dist GEMM
                        ushort4 h, l;
                        split2(o.x, h.x, l.x); split2(o.y, h.y, l.y);
                        split2(o.z, h.z, l.z); split2(o.w, h.w, l.w);
                        *reinterpret_cast<ushort4*>(zhi + gr * (long long)KP + gc) = h;
                        *reinterpret_cast<ushort4*>(zlo + gr * (long long)KP + gc) = l;
                    }
                } else {
                    const float4 ee = *reinterpret_cast<const float4*>(csq + gc);
                    o.x = zr - 2.0f * acc[i][jj + 0] + ee.x;
                    o.y = zr - 2.0f * acc[i][jj + 1] + ee.y;
                    o.z = zr - 2.0f * acc[i][jj + 2] + ee.z;
                    o.w = zr - 2.0f * acc[i][jj + 3] + ee.w;
                }
                *reinterpret_cast<float4*>(crow + gc) = o;
            }
        }
    }
}

// ---------------------------------------------------------------------------
// MFMA split-2 bf16 distance GEMM: dist[m,n] = zsq[m] - 2*(z.e) + esq[n]
// 128x128 tile, BK=32, 4 waves (2x2), 16x16x32 MFMA, 3 products (hh, hl, lh).
// LDS: 2 buffers x 4 tiles (Ahi,Alo,Bhi,Blo) of [128][32] bf16 (64B rows).
// XOR swizzle MUST stay inside the 64B row -> 2 bits only: byte ^= (r&3)<<4.
// Applied to the per-lane GLOBAL source address on stage (global_load_lds
// writes linearly, rule #21) and to the ds_read offset on the read side.
// ---------------------------------------------------------------------------
__global__ __launch_bounds__(256, 2)
void gemm2_mfma(const unsigned short* __restrict__ Ahi, const unsigned short* __restrict__ Alo,
                const unsigned short* __restrict__ Bhi, const unsigned short* __restrict__ Blo,
                const float* __restrict__ zsq, const float* __restrict__ esq,
                float* __restrict__ dist)
{
    constexpr int NT = KP / 32;   // 85
    __shared__ unsigned short lds[2][4][128 * 32];

    const int tid  = threadIdx.x;
    const int wid  = tid >> 6;
    const int lane = tid & 63;
    const int row0 = blockIdx.y << 7;
    const int col0 = blockIdx.x << 7;
    const int wr = wid >> 1, wc = wid & 1;

    f32x4 acc[4][4];
#pragma unroll
    for (int m = 0; m < 4; ++m)
#pragma unroll
        for (int n = 0; n < 4; ++n) acc[m][n] = (f32x4)0.0f;

    const unsigned short* srcs[4] = {Ahi, Alo, Bhi, Blo};

    auto stage = [&](int t, int b) {
        const int kt = t * 32;
#pragma unroll
        for (int T = 0; T < 4; ++T) {
            const int base = (T < 2) ? row0 : col0;
            const unsigned short* s = srcs[T];
#pragma unroll
            for (int q = 0; q < 2; ++q) {
                const int chunk = wid * 2 + q;                    // 0..7 (1KB each)
                const int r     = chunk * 16 + (lane >> 2);       // tile row 0..127
                const int inner = (lane & 3) << 4;                // byte in 64B row
                const int unswz = inner ^ ((r & 3) << 4);         // in-row involution
                const unsigned short* g = s + (size_t)(base + r) * KP + kt + (unswz >> 1);
                __builtin_amdgcn_global_load_lds(
                    (const __attribute__((address_space(1))) void*)g,
                    (__attribute__((address_space(3))) void*)(&lds[b][T][chunk * 512]),
                    16, 0, 0);
            }
        }
    };

    auto compute = [&](int b) {
        bf16x8 ah[4], al[4], bh[4], bl[4];
        const int kb = (lane >> 4) << 4;   // k byte offset: 0,16,32,48
#pragma unroll
        for (int m = 0; m < 4; ++m) {
            const int r   = wr * 64 + m * 16 + (lane & 15);
            const int off = r * 32 + ((kb ^ ((r & 3) << 4)) >> 1);
            ah[m] = *reinterpret_cast<const bf16x8*>(&lds[b][0][off]);
            al[m] = *reinterpret_cast<const bf16x8*>(&lds[b][1][off]);
        }
#pragma unroll
        for (int n = 0; n < 4; ++n) {
            const int r   = wc * 64 + n * 16 + (lane & 15);
            const int off = r * 32 + ((kb ^ ((r & 3) << 4)) >> 1);
            bh[n] = *reinterpret_cast<const bf16x8*>(&lds[b][2][off]);
            bl[n] = *reinterpret_cast<const bf16x8*>(&lds[b][3][off]);
        }
#pragma unroll
        for (int m = 0; m < 4; ++m)
#pragma unroll
            for (int n = 0; n < 4; ++n) {
                acc[m][n] = __builtin_amdgcn_mfma_f32_16x16x32_bf16(ah[m], bh[n], acc[m][n], 0, 0, 0);
                acc[m][n] = __builtin_amdgcn_mfma_f32_16x16x32_bf16(ah[m], bl[n], acc[m][n], 0, 0, 0);
                acc[m][n] = __builtin_amdgcn_mfma_f32_16x16x32_bf16(al[m], bh[n], acc[m][n], 0, 0, 0);
            }
    };

    stage(0, 0);
    __syncthreads();
    for (int t = 0; t < NT; ++t) {
        const int cur = t & 1;
        if (t + 1 < NT) stage(t + 1, cur ^ 1);
        compute(cur);
        __syncthreads();
    }

    // epilogue: C/D layout col=lane&15, row=(lane>>4)*4+reg  [m89]
#pragma unroll
    for (int m = 0; m < 4; ++m) {
        const int gr0 = row0 + wr * 64 + m * 16 + ((lane >> 4) << 2);
#pragma unroll
        for (int n = 0; n < 4; ++n) {
            const int gc = col0 + wc * 64 + n * 16 + (lane & 15);
            const float eq = esq[gc];
#pragma unroll
            for (int r = 0; r < 4; ++r) {
                const int gr = gr0 + r;
                dist[(size_t)gr * NCODES + gc] = zsq[gr] - 2.0f * acc[m][n][r] + eq;
            }
        }
    }
}

// ---------------------------------------------------------------------------
// embed fp32 -> bf16 hi/lo splits (K-padded to KP with zeros)
// ---------------------------------------------------------------------------
__global__ __launch_bounds__(256)
void esplit(const float* __restrict__ emb, unsigned short* __restrict__ ehi,
            unsigned short* __restrict__ elo)
{
    const int row = blockIdx.x;
    for (int g = threadIdx.x; g < KP / 4; g += 256) {
        const int c = g * 4;
        ushort4 h, l;
        if (c < BDIM) {
            const float4 v = *reinterpret_cast<const float4*>(emb + (size_t)row * BDIM + c);
            split2(v.x, h.x, l.x); split2(v.y, h.y, l.y);
            split2(v.z, h.z, l.z); split2(v.w, h.w, l.w);
        } else {
            h.x = h.y = h.z = h.w = 0; l = h;
        }
        *reinterpret_cast<ushort4*>(ehi + (size_t)row * KP + c) = h;
        *reinterpret_cast<ushort4*>(elo + (size_t)row * KP + c) = l;
    }
}

// zero the K-pad columns (2700..2719) of z_hi/z_lo (ws is poisoned each call)
__global__ void pad_z(unsigned short* __restrict__ zhi, unsigned short* __restrict__ zlo)
{
    const int i = blockIdx.x * 256 + threadIdx.x;
    if (i < M_ROWS * (KP - BDIM)) {
        const int r = i / (KP - BDIM);
        const int c = BDIM + i % (KP - BDIM);
        zhi[(size_t)r * KP + c] = 0;
        zlo[(size_t)r * KP + c] = 0;
    }
}

// ---------------------------------------------------------------------------
// Row-wise sum of squares
// ---------------------------------------------------------------------------
__global__ __launch_bounds__(256)
void rowsumsq(const float* __restrict__ src, float* __restrict__ out, int ncols)
{
    const int row = blockIdx.x;
    const float4* s = reinterpret_cast<const float4*>(src + (size_t)row * ncols);
    const int n4 = ncols >> 2;
    float acc = 0.0f;
    for (int i = threadIdx.x; i < n4; i += 256) {
        const float4 v = s[i];
        acc += v.x * v.x + v.y * v.y + v.z * v.z + v.w * v.w;
    }
    for (int off = 32; off; off >>= 1) acc += __shfl_down(acc, off);
    __shared__ float wsum[4];
    if ((threadIdx.x & 63) == 0) wsum[threadIdx.x >> 6] = acc;
    __syncthreads();
    if (threadIdx.x == 0) out[row] = wsum[0] + wsum[1] + wsum[2] + wsum[3];
}

// ---------------------------------------------------------------------------
// Per-row: two-smallest argmin (first-index tie-break), softmax sum, avg_prob
// atomics, index outputs, min-dist into sse, and best/second gap for refine.
// ---------------------------------------------------------------------------
__global__ __launch_bounds__(256)
void row_softmax(const float* __restrict__ dist, float* __restrict__ prob_acc,
                 float* __restrict__ sse, float* __restrict__ out_idx_f,
                 int* __restrict__ out_idx_i, float* __restrict__ gap_out)
{
    const int row = blockIdx.x;
    const int tid = threadIdx.x;
    const float4 d4 = reinterpret_cast<const float4*>(dist + (size_t)row * NCODES)[tid];
    const float dv[4] = {d4.x, d4.y, d4.z, d4.w};

    unsigned long long b0 = 0xFFFFFFFFFFFFFFFFull, b1 = 0xFFFFFFFFFFFFFFFFull;
#pragma unroll
    for (int j = 0; j < 4; ++j) {
        const unsigned long long k = pack_key(dv[j], tid * 4 + j);
        if (k < b0) { b1 = b0; b0 = k; } else if (k < b1) { b1 = k; }
    }
    for (int off = 1; off < 64; off <<= 1) {
        const unsigned long long o0 = __shfl_xor(b0, off);
        const unsigned long long o1 = __shfl_xor(b1, off);
        const unsigned long long nb0 = (b0 < o0) ? b0 : o0;
        const unsigned long long mx  = (b0 < o0) ? o0 : b0;
        const unsigned long long mn1 = (b1 < o1) ? b1 : o1;
        b0 = nb0;
        b1 = (mx < mn1) ? mx : mn1;
    }
    __shared__ unsigned long long wm0[4], wm1[4];
    __shared__ float wred[4];
    if ((tid & 63) == 0) { wm0[tid >> 6] = b0; wm1[tid >> 6] = b1; }
    __syncthreads();
    unsigned long long B0 = wm0[0], B1 = wm1[0];
#pragma unroll
    for (int w = 1; w < 4; ++w) {
        const unsigned long long o0 = wm0[w], o1 = wm1[w];
        const unsigned long long nb0 = (B0 < o0) ? B0 : o0;
        const unsigned long long mx  = (B0 < o0) ? o0 : B0;
        const unsigned long long mn1 = (B1 < o1) ? B1 : o1;
        B0 = nb0;
        B1 = (mx < mn1) ? mx : mn1;
    }
    const float m   = unpack_val(B0);
    const int   idx = (int)(B0 & 0xffffffffu);

    float e[4];
    float s_local = 0.0f;
#pragma unroll
    for (int j = 0; j < 4; ++j) { e[j] = expf(m - dv[j]); s_local += e[j]; }
    for (int off = 32; off; off >>= 1) s_local += __shfl_down(s_local, off);
    if ((tid & 63) == 0) wred[tid >> 6] = s_local;
    __syncthreads();
    const float S = wred[0] + wred[1] + wred[2] + wred[3];
    const float scale = (1.0f / S) * 0.0001220703125f;  // /S /8192
#pragma unroll
    for (int j = 0; j < 4; ++j)
        if (e[j] > 0.0f) atomicAdd(&prob_acc[tid * 4 + j], e[j] * scale);

    if (tid == 0) {
        out_idx_f[row] = (float)idx;
        out_idx_i[row] = idx;
        gap_out[row]   = unpack_val(B1) - m;
        atomicAdd(sse, m);
    }
}

// ---------------------------------------------------------------------------
// Exact fp32 re-argmin for rows whose approx gap < DELTA (expected ~50 rows).
// Deterministic split-2 error bound ~0.04 per dot -> 2*err + margin < 0.25.
// ---------------------------------------------------------------------------
static constexpr float DELTA = 0.25f;

__global__ __launch_bounds__(256)
void refine_rows(const float* __restrict__ Zf, const float* __restrict__ emb,
                 const float* __restrict__ gap, const float* __restrict__ zsq,
                 const float* __restrict__ esq, float* __restrict__ out_idx_f,
                 int* __restrict__ out_idx_i)
{
    const int row = blockIdx.x;
    if (gap[row] >= DELTA) return;      // block-uniform
    const int tid = threadIdx.x;
    __shared__ float zrow[BDIM];
    for (int i = tid; i < BDIM; i += 256) zrow[i] = Zf[(size_t)row * BDIM + i];
    __syncthreads();
    const float zq = zsq[row];
    unsigned long long best = 0xFFFFFFFFFFFFFFFFull;
#pragma unroll 1
    for (int c = 0; c < 4; ++c) {
        const int code = tid + c * 256;
        const float4* er = reinterpret_cast<const float4*>(emb + (size_t)code * BDIM);
        float a0 = 0, a1 = 0, a2 = 0, a3 = 0;
        for (int k = 0; k < BDIM / 4; ++k) {
            const float4 e4 = er[k];
            const float4 z4 = *reinterpret_cast<const float4*>(&zrow[k * 4]);
            a0 = __builtin_fmaf(z4.x, e4.x, a0);
            a1 = __builtin_fmaf(z4.y, e4.y, a1);
            a2 = __builtin_fmaf(z4.z, e4.z, a2);
            a3 = __builtin_fmaf(z4.w, e4.w, a3);
        }
        const float t = (a0 + a1) + (a2 + a3);
        const float d = zq - 2.0f * t + esq[code];
        const unsigned long long k = pack_key(d, code);
        if (k < best) best = k;
    }
    for (int off = 32; off; off >>= 1) {
        const unsigned long long o = __shfl_down(best, off);
        if (o < best) best = o;
    }
    __shared__ unsigned long long wmin[4];
    if ((tid & 63) == 0) wmin[tid >> 6] = best;
    __syncthreads();
    if (tid == 0) {
        unsigned long long b = wmin[0];
        if (wmin[1] < b) b = wmin[1];
        if (wmin[2] < b) b = wmin[2];
        if (wmin[3] < b) b = wmin[3];
        const int idx = (int)(b & 0xffffffffu);
        out_idx_f[row] = (float)idx;
        out_idx_i[row] = idx;
    }
}

// ---------------------------------------------------------------------------
// q_st[n,:] = embed[idx[n],:]
// ---------------------------------------------------------------------------
__global__ __launch_bounds__(256)
void gather_q(const float* __restrict__ embed, const int* __restrict__ idx,
              float* __restrict__ q)
{
    const int row  = blockIdx.x;
    const int code = idx[row];
    const float4* s = reinterpret_cast<const float4*>(embed + (size_t)code * BDIM);
    float4*       d = reinterpret_cast<float4*>(q + (size_t)row * BDIM);
    for (int i = threadIdx.x; i < (BDIM >> 2); i += 256) d[i] = s[i];
}

__global__ void init_ws(float* __restrict__ prob_acc, float* __restrict__ sse)
{
    const int t = threadIdx.x;
    if (t < NCODES) prob_acc[t] = 0.0f;
    if (t == 0) sse[0] = 0.0f;
}

__global__ __launch_bounds__(256)
void finalize(const float* __restrict__ prob_acc, const float* __restrict__ sse,
              float* __restrict__ out)
{
    const int tid = threadIdx.x;
    float ent = 0.0f;
    for (int c = tid; c < NCODES; c += 256) {
        const float a = prob_acc[c];
        ent -= a * logf(a + 1e-8f);
    }
    for (int off = 32; off; off >>= 1) ent += __shfl_down(ent, off);
    __shared__ float wred[4];
    if ((tid & 63) == 0) wred[tid >> 6] = ent;
    __syncthreads();
    if (tid == 0) {
        out[QST_N + M_ROWS + 0] = sse[0] / 22118400.0f;
        out[QST_N + M_ROWS + 1] = wred[0] + wred[1] + wred[2] + wred[3];
    }
}

extern "C" void kernel_launch(void* const* d_in, const int* in_sizes, int n_in,
                              void* d_out, int out_size, void* d_ws, size_t ws_size,
                              hipStream_t stream)
{
    (void)in_sizes; (void)n_in; (void)out_size;
    const float* slot = (const float*)d_in[0];
    const float* W    = (const float*)d_in[1];
    const float* bpr  = (const float*)d_in[2];
    const float* emb  = (const float*)d_in[3];

    float* out  = (float*)d_out;
    float* Z    = out;              // z_e lives in the q_st region until gather
    float* idxf = out + QST_N;

    // ---- workspace layout ----
    const size_t DIST_B = (size_t)M_ROWS * NCODES * 4;          // 33,554,432
    const size_t ZSPL_B = (size_t)M_ROWS * KP * 2;              // 44,564,480
    const size_t ESPL_B = (size_t)NCODES * KP * 2;              //  5,570,560
    const size_t REQUIRED = DIST_B + 2 * ZSPL_B + 2 * ESPL_B + (1u << 20);
    const bool use_mfma = ws_size >= REQUIRED;

    char* w = (char*)d_ws;
    float* dist = (float*)w;                         w += DIST_B;
    unsigned short *zhi = nullptr, *zlo = nullptr, *ehi = nullptr, *elo = nullptr;
    if (use_mfma) {
        zhi = (unsigned short*)w;  w += ZSPL_B;
        zlo = (unsigned short*)w;  w += ZSPL_B;
        ehi = (unsigned short*)w;  w += ESPL_B;
        elo = (unsigned short*)w;  w += ESPL_B;
    }
    float* zsq  = (float*)w;                         w += (size_t)M_ROWS * 4;
    float* esq  = (float*)w;                         w += (size_t)NCODES * 4;
    float* gap  = (float*)w;                         w += (size_t)M_ROWS * 4;
    int*   idxi = (int*)w;                           w += (size_t)M_ROWS * 4;
    float* prob = (float*)w;                         w += (size_t)NCODES * 4;
    float* sse  = (float*)w;

    init_ws<<<1, 1024, 0, stream>>>(prob, sse);
    rowsumsq<<<NCODES, 256, 0, stream>>>(emb, esq, BDIM);
    if (use_mfma)
        esplit<<<NCODES, 256, 0, stream>>>(emb, ehi, elo);

    gemm_nt<0><<<dim3((BDIM + 127) / 128, M_ROWS / 128), 256, 0, stream>>>(
        slot, W, bpr, nullptr, nullptr, Z, BDIM, DMODEL, DMODEL, DMODEL, BDIM,
        zhi, zlo);
    rowsumsq<<<M_ROWS, 256, 0, stream>>>(Z, zsq, BDIM);

    if (use_mfma) {
        pad_z<<<(M_ROWS * (KP - BDIM) + 255) / 256, 256, 0, stream>>>(zhi, zlo);
        gemm2_mfma<<<dim3(NCODES / 128, M_ROWS / 128), 256, 0, stream>>>(
            zhi, zlo, ehi, elo, zsq, esq, dist);
    } else {
        gemm_nt<1><<<dim3(NCODES / 128, M_ROWS / 128), 256, 0, stream>>>(
            Z, emb, nullptr, zsq, esq, dist, NCODES, BDIM, BDIM, BDIM, NCODES,
            nullptr, nullptr);
    }

    row_softmax<<<M_ROWS, 256, 0, stream>>>(dist, prob, sse, idxf, idxi, gap);
    refine_rows<<<M_ROWS, 256, 0, stream>>>(Z, emb, gap, zsq, esq, idxf, idxi);
    gather_q<<<M_ROWS, 256, 0, stream>>>(emb, idxi, Z);
    finalize<<<1, 256, 0, stream>>>(prob, sse, out);
}

// Round 4
// 581.730 us; speedup vs baseline: 1.7700x; 1.7471x over previous
//
#include <hip/hip_runtime.h>
#include <stdint.h>
#include <stddef.h>

// Problem geometry (fixed by setup_inputs)
static constexpr int    M_ROWS = 8192;   // B*K
static constexpr int    DMODEL = 256;
static constexpr int    BDIM   = 2700;
static constexpr int    NCODES = 1024;
static constexpr int    KP     = 2720;   // BDIM padded to multiple of 32 (85 K-steps)
static constexpr size_t QST_N  = (size_t)M_ROWS * (size_t)BDIM;  // 22118400
static constexpr int    MAX_CAND = 32768;

typedef __bf16 bf16x8 __attribute__((ext_vector_type(8)));
typedef float  f32x4  __attribute__((ext_vector_type(4)));

// ---------------------------------------------------------------------------
// helpers: fp32 -> bf16 split (RNE), argmin key packing
// ---------------------------------------------------------------------------
__device__ inline unsigned short bf16h(float x) {
    unsigned u = __float_as_uint(x);
    unsigned r = u + 0x7fffu + ((u >> 16) & 1u);
    return (unsigned short)(r >> 16);
}
__device__ inline void split2(float x, unsigned short& h, unsigned short& l) {
    h = bf16h(x);
    const float hf = __uint_as_float(((unsigned)h) << 16);
    l = bf16h(x - hf);
}
__device__ inline unsigned long long pack_key(float v, int idx) {
    unsigned u = __float_as_uint(v);
    unsigned k = (u & 0x80000000u) ? ~u : (u | 0x80000000u);
    return ((unsigned long long)k << 32) | (unsigned)idx;
}
__device__ inline float unpack_val(unsigned long long key) {
    unsigned ku = (unsigned)(key >> 32);
    return (ku & 0x80000000u) ? __uint_as_float(ku & 0x7fffffffu)
                              : __uint_as_float(~ku);
}

// ---------------------------------------------------------------------------
// Tiled fp32 NT-GEMM: MODE 0 writes z (+ optional bf16 hi/lo splits),
// MODE 1 is the fp32 fallback distance GEMM.
// ---------------------------------------------------------------------------
template<int MODE>
__global__ __launch_bounds__(256, 2)
void gemm_nt(const float* __restrict__ A, const float* __restrict__ B,
             const float* __restrict__ bias,
             const float* __restrict__ rsq, const float* __restrict__ csq,
             float* __restrict__ C, int Ndim, int Kdim, int lda, int ldb, int ldc,
             unsigned short* __restrict__ zhi, unsigned short* __restrict__ zlo)
{
    constexpr int BK = 16;
    constexpr int LS = 132;
    __shared__ float As[2][BK][LS];
    __shared__ float Bs[2][BK][LS];

    const int tid  = threadIdx.x;
    const int row0 = blockIdx.y << 7;
    const int col0 = blockIdx.x << 7;

    const int sm = tid >> 2;
    const int sk = (tid & 3) << 2;

    const int wid  = tid >> 6;
    const int lane = tid & 63;
    const int tr = ((wid >> 1) << 6) | ((lane >> 3) << 3);
    const int tc = ((wid & 1) << 6) | ((lane & 7) << 3);

    float acc[8][8];
#pragma unroll
    for (int i = 0; i < 8; ++i)
#pragma unroll
        for (int j = 0; j < 8; ++j) acc[i][j] = 0.0f;

    const int nt = (Kdim + BK - 1) / BK;

    auto stage = [&](int t, int buf) {
        const int  kt    = t * BK;
        const bool kfull = (kt + BK) <= Kdim;
#pragma unroll
        for (int half = 0; half < 2; ++half) {
            const int m = sm + (half << 6);
            {
                const long long gr = row0 + m;
                const float* ap = A + gr * (long long)lda + kt + sk;
                float4 v;
                if (kfull) {
                    v = *reinterpret_cast<const float4*>(ap);
                } else {
                    v.x = (kt + sk + 0 < Kdim) ? ap[0] : 0.0f;
                    v.y = (kt + sk + 1 < Kdim) ? ap[1] : 0.0f;
                    v.z = (kt + sk + 2 < Kdim) ? ap[2] : 0.0f;
                    v.w = (kt + sk + 3 < Kdim) ? ap[3] : 0.0f;
                }
                As[buf][sk + 0][m] = v.x; As[buf][sk + 1][m] = v.y;
                As[buf][sk + 2][m] = v.z; As[buf][sk + 3][m] = v.w;
            }
            {
                const long long gc = col0 + m;
                float4 v; v.x = v.y = v.z = v.w = 0.0f;
                if (gc < Ndim) {
                    const float* bp = B + gc * (long long)ldb + kt + sk;
                    if (kfull) {
                        v = *reinterpret_cast<const float4*>(bp);
                    } else {
                        v.x = (kt + sk + 0 < Kdim) ? bp[0] : 0.0f;
                        v.y = (kt + sk + 1 < Kdim) ? bp[1] : 0.0f;
                        v.z = (kt + sk + 2 < Kdim) ? bp[2] : 0.0f;
                        v.w = (kt + sk + 3 < Kdim) ? bp[3] : 0.0f;
                    }
                }
                Bs[buf][sk + 0][m] = v.x; Bs[buf][sk + 1][m] = v.y;
                Bs[buf][sk + 2][m] = v.z; Bs[buf][sk + 3][m] = v.w;
            }
        }
    };

    stage(0, 0);
    __syncthreads();
    for (int t = 0; t < nt; ++t) {
        const int buf = t & 1;
        if (t + 1 < nt) stage(t + 1, buf ^ 1);
#pragma unroll
        for (int kk = 0; kk < BK; ++kk) {
            const float4 a0 = *reinterpret_cast<const float4*>(&As[buf][kk][tr]);
            const float4 a1 = *reinterpret_cast<const float4*>(&As[buf][kk][tr + 4]);
            const float4 b0 = *reinterpret_cast<const float4*>(&Bs[buf][kk][tc]);
            const float4 b1 = *reinterpret_cast<const float4*>(&Bs[buf][kk][tc + 4]);
            const float av[8] = {a0.x, a0.y, a0.z, a0.w, a1.x, a1.y, a1.z, a1.w};
            const float bv[8] = {b0.x, b0.y, b0.z, b0.w, b1.x, b1.y, b1.z, b1.w};
#pragma unroll
            for (int i = 0; i < 8; ++i)
#pragma unroll
                for (int j = 0; j < 8; ++j)
                    acc[i][j] = __builtin_fmaf(av[i], bv[j], acc[i][j]);
        }
        __syncthreads();
    }

#pragma unroll
    for (int i = 0; i < 8; ++i) {
        const long long gr = row0 + tr + i;
        float* crow = C + gr * (long long)ldc;
        float zr = 0.0f;
        if constexpr (MODE == 1) zr = rsq[gr];
#pragma unroll
        for (int jj = 0; jj < 8; jj += 4) {
            const int gc = col0 + tc + jj;
            if (gc + 4 <= Ndim) {
                float4 o;
                if constexpr (MODE == 0) {
                    const float4 bb = *reinterpret_cast<const float4*>(bias + gc);
                    o.x = acc[i][jj + 0] + bb.x;
                    o.y = acc[i][jj + 1] + bb.y;
                    o.z = acc[i][jj + 2] + bb.z;
                    o.w = acc[i][jj + 3] + bb.w;
                    if (zhi) {   // bf16 split-2 of z for the MFMA dist GEMM
                        ushort4 h, l;
                        split2(o.x, h.x, l.x); split2(o.y, h.y, l.y);
                        split2(o.z, h.z, l.z); split2(o.w, h.w, l.w);
                        *reinterpret_cast<ushort4*>(zhi + gr * (long long)KP + gc) = h;
                        *reinterpret_cast<ushort4*>(zlo + gr * (long long)KP + gc) = l;
                    }
                } else {
                    const float4 ee = *reinterpret_cast<const float4*>(csq + gc);
                    o.x = zr - 2.0f * acc[i][jj + 0] + ee.x;
                    o.y = zr - 2.0f * acc[i][jj + 1] + ee.y;
                    o.z = zr - 2.0f * acc[i][jj + 2] + ee.z;
                    o.w = zr - 2.0f * acc[i][jj + 3] + ee.w;
                }
                *reinterpret_cast<float4*>(crow + gc) = o;
            }
        }
    }
}

// ---------------------------------------------------------------------------
// MFMA split-2 bf16 distance GEMM: dist[m,n] = zsq[m] - 2*(z.e) + esq[n]
// 128x128 tile, BK=32, 4 waves (2x2), 16x16x32 MFMA, 3 products (hh, hl, lh).
// In-row XOR involution byte ^= (r&3)<<4 applied BOTH on the pre-swizzled
// global source (global_load_lds writes linearly) and on the ds_read offset.
// ---------------------------------------------------------------------------
__global__ __launch_bounds__(256, 2)
void gemm2_mfma(const unsigned short* __restrict__ Ahi, const unsigned short* __restrict__ Alo,
                const unsigned short* __restrict__ Bhi, const unsigned short* __restrict__ Blo,
                const float* __restrict__ zsq, const float* __restrict__ esq,
                float* __restrict__ dist)
{
    constexpr int NT = KP / 32;   // 85
    __shared__ unsigned short lds[2][4][128 * 32];

    const int tid  = threadIdx.x;
    const int wid  = tid >> 6;
    const int lane = tid & 63;
    const int row0 = blockIdx.y << 7;
    const int col0 = blockIdx.x << 7;
    const int wr = wid >> 1, wc = wid & 1;

    f32x4 acc[4][4];
#pragma unroll
    for (int m = 0; m < 4; ++m)
#pragma unroll
        for (int n = 0; n < 4; ++n) acc[m][n] = (f32x4)0.0f;

    const unsigned short* srcs[4] = {Ahi, Alo, Bhi, Blo};

    auto stage = [&](int t, int b) {
        const int kt = t * 32;
#pragma unroll
        for (int T = 0; T < 4; ++T) {
            const int base = (T < 2) ? row0 : col0;
            const unsigned short* s = srcs[T];
#pragma unroll
            for (int q = 0; q < 2; ++q) {
                const int chunk = wid * 2 + q;                    // 0..7 (1KB each)
                const int r     = chunk * 16 + (lane >> 2);       // tile row 0..127
                const int inner = (lane & 3) << 4;                // byte in 64B row
                const int unswz = inner ^ ((r & 3) << 4);         // in-row involution
                const unsigned short* g = s + (size_t)(base + r) * KP + kt + (unswz >> 1);
                __builtin_amdgcn_global_load_lds(
                    (const __attribute__((address_space(1))) void*)g,
                    (__attribute__((address_space(3))) void*)(&lds[b][T][chunk * 512]),
                    16, 0, 0);
            }
        }
    };

    auto compute = [&](int b) {
        bf16x8 ah[4], al[4], bh[4], bl[4];
        const int kb = (lane >> 4) << 4;   // k byte offset: 0,16,32,48
#pragma unroll
        for (int m = 0; m < 4; ++m) {
            const int r   = wr * 64 + m * 16 + (lane & 15);
            const int off = r * 32 + ((kb ^ ((r & 3) << 4)) >> 1);
            ah[m] = *reinterpret_cast<const bf16x8*>(&lds[b][0][off]);
            al[m] = *reinterpret_cast<const bf16x8*>(&lds[b][1][off]);
        }
#pragma unroll
        for (int n = 0; n < 4; ++n) {
            const int r   = wc * 64 + n * 16 + (lane & 15);
            const int off = r * 32 + ((kb ^ ((r & 3) << 4)) >> 1);
            bh[n] = *reinterpret_cast<const bf16x8*>(&lds[b][2][off]);
            bl[n] = *reinterpret_cast<const bf16x8*>(&lds[b][3][off]);
        }
#pragma unroll
        for (int m = 0; m < 4; ++m)
#pragma unroll
            for (int n = 0; n < 4; ++n) {
                acc[m][n] = __builtin_amdgcn_mfma_f32_16x16x32_bf16(ah[m], bh[n], acc[m][n], 0, 0, 0);
                acc[m][n] = __builtin_amdgcn_mfma_f32_16x16x32_bf16(ah[m], bl[n], acc[m][n], 0, 0, 0);
                acc[m][n] = __builtin_amdgcn_mfma_f32_16x16x32_bf16(al[m], bh[n], acc[m][n], 0, 0, 0);
            }
    };

    stage(0, 0);
    __syncthreads();
    for (int t = 0; t < NT; ++t) {
        const int cur = t & 1;
        if (t + 1 < NT) stage(t + 1, cur ^ 1);
        compute(cur);
        __syncthreads();
    }

    // epilogue: C/D layout col=lane&15, row=(lane>>4)*4+reg  [m89]
#pragma unroll
    for (int m = 0; m < 4; ++m) {
        const int gr0 = row0 + wr * 64 + m * 16 + ((lane >> 4) << 2);
#pragma unroll
        for (int n = 0; n < 4; ++n) {
            const int gc = col0 + wc * 64 + n * 16 + (lane & 15);
            const float eq = esq[gc];
#pragma unroll
            for (int r = 0; r < 4; ++r) {
                const int gr = gr0 + r;
                dist[(size_t)gr * NCODES + gc] = zsq[gr] - 2.0f * acc[m][n][r] + eq;
            }
        }
    }
}

// ---------------------------------------------------------------------------
// embed fp32 -> bf16 hi/lo splits (K-padded to KP with zeros)
// ---------------------------------------------------------------------------
__global__ __launch_bounds__(256)
void esplit(const float* __restrict__ emb, unsigned short* __restrict__ ehi,
            unsigned short* __restrict__ elo)
{
    const int row = blockIdx.x;
    for (int g = threadIdx.x; g < KP / 4; g += 256) {
        const int c = g * 4;
        ushort4 h, l;
        if (c < BDIM) {
            const float4 v = *reinterpret_cast<const float4*>(emb + (size_t)row * BDIM + c);
            split2(v.x, h.x, l.x); split2(v.y, h.y, l.y);
            split2(v.z, h.z, l.z); split2(v.w, h.w, l.w);
        } else {
            h.x = h.y = h.z = h.w = 0; l = h;
        }
        *reinterpret_cast<ushort4*>(ehi + (size_t)row * KP + c) = h;
        *reinterpret_cast<ushort4*>(elo + (size_t)row * KP + c) = l;
    }
}

// zero the K-pad columns (2700..2719) of z_hi/z_lo (ws is poisoned each call)
__global__ void pad_z(unsigned short* __restrict__ zhi, unsigned short* __restrict__ zlo)
{
    const int i = blockIdx.x * 256 + threadIdx.x;
    if (i < M_ROWS * (KP - BDIM)) {
        const int r = i / (KP - BDIM);
        const int c = BDIM + i % (KP - BDIM);
        zhi[(size_t)r * KP + c] = 0;
        zlo[(size_t)r * KP + c] = 0;
    }
}

// ---------------------------------------------------------------------------
// Row-wise sum of squares
// ---------------------------------------------------------------------------
__global__ __launch_bounds__(256)
void rowsumsq(const float* __restrict__ src, float* __restrict__ out, int ncols)
{
    const int row = blockIdx.x;
    const float4* s = reinterpret_cast<const float4*>(src + (size_t)row * ncols);
    const int n4 = ncols >> 2;
    float acc = 0.0f;
    for (int i = threadIdx.x; i < n4; i += 256) {
        const float4 v = s[i];
        acc += v.x * v.x + v.y * v.y + v.z * v.z + v.w * v.w;
    }
    for (int off = 32; off; off >>= 1) acc += __shfl_down(acc, off);
    __shared__ float wsum[4];
    if ((threadIdx.x & 63) == 0) wsum[threadIdx.x >> 6] = acc;
    __syncthreads();
    if (threadIdx.x == 0) out[row] = wsum[0] + wsum[1] + wsum[2] + wsum[3];
}

// ---------------------------------------------------------------------------
// Per-row: two-smallest argmin, softmax sum, avg_prob atomics, index outputs,
// min-dist into sse, and CANDIDATE APPEND for ambiguous rows (gap < DELTA):
// every code within DELTA of the row min goes to a global (row,code) list.
// ---------------------------------------------------------------------------
static constexpr float DELTA = 0.25f;

__global__ __launch_bounds__(256)
void row_softmax(const float* __restrict__ dist, float* __restrict__ prob_acc,
                 float* __restrict__ sse, float* __restrict__ out_idx_f,
                 int* __restrict__ out_idx_i, float* __restrict__ gap_out,
                 unsigned* __restrict__ cand, int* __restrict__ cand_count,
                 unsigned long long* __restrict__ row_best)
{
    const int row = blockIdx.x;
    const int tid = threadIdx.x;
    const float4 d4 = reinterpret_cast<const float4*>(dist + (size_t)row * NCODES)[tid];
    const float dv[4] = {d4.x, d4.y, d4.z, d4.w};

    unsigned long long b0 = 0xFFFFFFFFFFFFFFFFull, b1 = 0xFFFFFFFFFFFFFFFFull;
#pragma unroll
    for (int j = 0; j < 4; ++j) {
        const unsigned long long k = pack_key(dv[j], tid * 4 + j);
        if (k < b0) { b1 = b0; b0 = k; } else if (k < b1) { b1 = k; }
    }
    for (int off = 1; off < 64; off <<= 1) {
        const unsigned long long o0 = __shfl_xor(b0, off);
        const unsigned long long o1 = __shfl_xor(b1, off);
        const unsigned long long nb0 = (b0 < o0) ? b0 : o0;
        const unsigned long long mx  = (b0 < o0) ? o0 : b0;
        const unsigned long long mn1 = (b1 < o1) ? b1 : o1;
        b0 = nb0;
        b1 = (mx < mn1) ? mx : mn1;
    }
    __shared__ unsigned long long wm0[4], wm1[4];
    __shared__ float wred[4];
    if ((tid & 63) == 0) { wm0[tid >> 6] = b0; wm1[tid >> 6] = b1; }
    __syncthreads();
    unsigned long long B0 = wm0[0], B1 = wm1[0];
#pragma unroll
    for (int w = 1; w < 4; ++w) {
        const unsigned long long o0 = wm0[w], o1 = wm1[w];
        const unsigned long long nb0 = (B0 < o0) ? B0 : o0;
        const unsigned long long mx  = (B0 < o0) ? o0 : B0;
        const unsigned long long mn1 = (B1 < o1) ? B1 : o1;
        B0 = nb0;
        B1 = (mx < mn1) ? mx : mn1;
    }
    const float m   = unpack_val(B0);
    const int   idx = (int)(B0 & 0xffffffffu);
    const float gap = unpack_val(B1) - m;

    // ambiguous rows: enqueue every candidate within DELTA of the min
    if (gap < DELTA) {
        if (tid == 0) row_best[row] = 0xFFFFFFFFFFFFFFFFull;
#pragma unroll
        for (int j = 0; j < 4; ++j) {
            if (dv[j] - m < DELTA) {
                const int slot = atomicAdd(cand_count, 1);
                if (slot < MAX_CAND)
                    cand[slot] = ((unsigned)row << 10) | (unsigned)(tid * 4 + j);
            }
        }
    }

    float e[4];
    float s_local = 0.0f;
#pragma unroll
    for (int j = 0; j < 4; ++j) { e[j] = expf(m - dv[j]); s_local += e[j]; }
    for (int off = 32; off; off >>= 1) s_local += __shfl_down(s_local, off);
    if ((tid & 63) == 0) wred[tid >> 6] = s_local;
    __syncthreads();
    const float S = wred[0] + wred[1] + wred[2] + wred[3];
    const float scale = (1.0f / S) * 0.0001220703125f;  // /S /8192
#pragma unroll
    for (int j = 0; j < 4; ++j)
        if (e[j] > 0.0f) atomicAdd(&prob_acc[tid * 4 + j], e[j] * scale);

    if (tid == 0) {
        out_idx_f[row] = (float)idx;
        out_idx_i[row] = idx;
        gap_out[row]   = gap;
        atomicAdd(sse, m);
    }
}

// ---------------------------------------------------------------------------
// Exact fp32 dist for each candidate (one WAVE per (row,code) pair):
// lane-parallel dot over 2700 dims, shuffle reduce, atomicMin packed key.
// ---------------------------------------------------------------------------
__global__ __launch_bounds__(256)
void refine2(const float* __restrict__ Zf, const float* __restrict__ emb,
             const unsigned* __restrict__ cand, const int* __restrict__ cand_count,
             const float* __restrict__ zsq, const float* __restrict__ esq,
             unsigned long long* __restrict__ row_best)
{
    const int nwaves = gridDim.x * 4;
    const int wglob  = blockIdx.x * 4 + (threadIdx.x >> 6);
    const int lane   = threadIdx.x & 63;
    const int n = min(*cand_count, MAX_CAND);
    for (int e = wglob; e < n; e += nwaves) {
        const unsigned pc  = cand[e];
        const int row  = (int)(pc >> 10);
        const int code = (int)(pc & 1023u);
        const float4* zp = reinterpret_cast<const float4*>(Zf + (size_t)row * BDIM);
        const float4* ep = reinterpret_cast<const float4*>(emb + (size_t)code * BDIM);
        float a0 = 0, a1 = 0, a2 = 0, a3 = 0;
        for (int k = lane; k < BDIM / 4; k += 64) {
            const float4 z4 = zp[k];
            const float4 e4 = ep[k];
            a0 = __builtin_fmaf(z4.x, e4.x, a0);
            a1 = __builtin_fmaf(z4.y, e4.y, a1);
            a2 = __builtin_fmaf(z4.z, e4.z, a2);
            a3 = __builtin_fmaf(z4.w, e4.w, a3);
        }
        float t = (a0 + a1) + (a2 + a3);
        for (int off = 32; off; off >>= 1) t += __shfl_down(t, off);
        if (lane == 0) {
            const float d = zsq[row] - 2.0f * t + esq[code];
            atomicMin(&row_best[row], pack_key(d, code));
        }
    }
}

// write refined indices back (rows flagged ambiguous only)
__global__ __launch_bounds__(256)
void fixup(const float* __restrict__ gap, const unsigned long long* __restrict__ row_best,
           float* __restrict__ out_idx_f, int* __restrict__ out_idx_i)
{
    const int row = blockIdx.x * 256 + threadIdx.x;
    if (row < M_ROWS && gap[row] < DELTA) {
        const unsigned long long k = row_best[row];
        if (k != 0xFFFFFFFFFFFFFFFFull) {   // guard truncated-list corner
            const int idx = (int)(k & 0xffffffffu);
            out_idx_f[row] = (float)idx;
            out_idx_i[row] = idx;
        }
    }
}

// ---------------------------------------------------------------------------
// q_st[n,:] = embed[idx[n],:]
// ---------------------------------------------------------------------------
__global__ __launch_bounds__(256)
void gather_q(const float* __restrict__ embed, const int* __restrict__ idx,
              float* __restrict__ q)
{
    const int row  = blockIdx.x;
    const int code = idx[row];
    const float4* s = reinterpret_cast<const float4*>(embed + (size_t)code * BDIM);
    float4*       d = reinterpret_cast<float4*>(q + (size_t)row * BDIM);
    for (int i = threadIdx.x; i < (BDIM >> 2); i += 256) d[i] = s[i];
}

__global__ void init_ws(float* __restrict__ prob_acc, float* __restrict__ sse,
                        int* __restrict__ cand_count)
{
    const int t = threadIdx.x;
    if (t < NCODES) prob_acc[t] = 0.0f;
    if (t == 0) { sse[0] = 0.0f; cand_count[0] = 0; }
}

__global__ __launch_bounds__(256)
void finalize(const float* __restrict__ prob_acc, const float* __restrict__ sse,
              float* __restrict__ out)
{
    const int tid = threadIdx.x;
    float ent = 0.0f;
    for (int c = tid; c < NCODES; c += 256) {
        const float a = prob_acc[c];
        ent -= a * logf(a + 1e-8f);
    }
    for (int off = 32; off; off >>= 1) ent += __shfl_down(ent, off);
    __shared__ float wred[4];
    if ((tid & 63) == 0) wred[tid >> 6] = ent;
    __syncthreads();
    if (tid == 0) {
        out[QST_N + M_ROWS + 0] = sse[0] / 22118400.0f;
        out[QST_N + M_ROWS + 1] = wred[0] + wred[1] + wred[2] + wred[3];
    }
}

extern "C" void kernel_launch(void* const* d_in, const int* in_sizes, int n_in,
                              void* d_out, int out_size, void* d_ws, size_t ws_size,
                              hipStream_t stream)
{
    (void)in_sizes; (void)n_in; (void)out_size;
    const float* slot = (const float*)d_in[0];
    const float* W    = (const float*)d_in[1];
    const float* bpr  = (const float*)d_in[2];
    const float* emb  = (const float*)d_in[3];

    float* out  = (float*)d_out;
    float* Z    = out;              // z_e lives in the q_st region until gather
    float* idxf = out + QST_N;

    // ---- workspace layout ----
    const size_t DIST_B = (size_t)M_ROWS * NCODES * 4;          // 33,554,432
    const size_t ZSPL_B = (size_t)M_ROWS * KP * 2;              // 44,564,480
    const size_t ESPL_B = (size_t)NCODES * KP * 2;              //  5,570,560
    const size_t REQUIRED = DIST_B + 2 * ZSPL_B + 2 * ESPL_B + (1u << 20);
    const bool use_mfma = ws_size >= REQUIRED;

    char* w = (char*)d_ws;
    float* dist = (float*)w;                         w += DIST_B;
    unsigned short *zhi = nullptr, *zlo = nullptr, *ehi = nullptr, *elo = nullptr;
    if (use_mfma) {
        zhi = (unsigned short*)w;  w += ZSPL_B;
        zlo = (unsigned short*)w;  w += ZSPL_B;
        ehi = (unsigned short*)w;  w += ESPL_B;
        elo = (unsigned short*)w;  w += ESPL_B;
    }
    float* zsq  = (float*)w;                          w += (size_t)M_ROWS * 4;
    float* esq  = (float*)w;                          w += (size_t)NCODES * 4;
    float* gap  = (float*)w;                          w += (size_t)M_ROWS * 4;
    int*   idxi = (int*)w;                            w += (size_t)M_ROWS * 4;
    float* prob = (float*)w;                          w += (size_t)NCODES * 4;
    float* sse  = (float*)w;                          w += 256;
    unsigned long long* rbest = (unsigned long long*)w; w += (size_t)M_ROWS * 8;
    unsigned* cand = (unsigned*)w;                    w += (size_t)MAX_CAND * 4;
    int* ccount = (int*)w;

    init_ws<<<1, 1024, 0, stream>>>(prob, sse, ccount);
    rowsumsq<<<NCODES, 256, 0, stream>>>(emb, esq, BDIM);
    if (use_mfma)
        esplit<<<NCODES, 256, 0, stream>>>(emb, ehi, elo);

    gemm_nt<0><<<dim3((BDIM + 127) / 128, M_ROWS / 128), 256, 0, stream>>>(
        slot, W, bpr, nullptr, nullptr, Z, BDIM, DMODEL, DMODEL, DMODEL, BDIM,
        zhi, zlo);
    rowsumsq<<<M_ROWS, 256, 0, stream>>>(Z, zsq, BDIM);

    if (use_mfma) {
        pad_z<<<(M_ROWS * (KP - BDIM) + 255) / 256, 256, 0, stream>>>(zhi, zlo);
        gemm2_mfma<<<dim3(NCODES / 128, M_ROWS / 128), 256, 0, stream>>>(
            zhi, zlo, ehi, elo, zsq, esq, dist);
    } else {
        gemm_nt<1><<<dim3(NCODES / 128, M_ROWS / 128), 256, 0, stream>>>(
            Z, emb, nullptr, zsq, esq, dist, NCODES, BDIM, BDIM, BDIM, NCODES,
            nullptr, nullptr);
    }

    row_softmax<<<M_ROWS, 256, 0, stream>>>(dist, prob, sse, idxf, idxi, gap,
                                            cand, ccount, rbest);
    refine2<<<128, 256, 0, stream>>>(Z, emb, cand, ccount, zsq, esq, rbest);
    fixup<<<M_ROWS / 256, 256, 0, stream>>>(gap, rbest, idxf, idxi);
    gather_q<<<M_ROWS, 256, 0, stream>>>(emb, idxi, Z);
    finalize<<<1, 256, 0, stream>>>(prob, sse, out);
}

// Round 5
// 492.691 us; speedup vs baseline: 2.0899x; 1.1807x over previous
//
#include <hip/hip_runtime.h>
#include <stdint.h>
#include <stddef.h>

// Problem geometry (fixed by setup_inputs)
static constexpr int    M_ROWS = 8192;   // B*K
static constexpr int    DMODEL = 256;
static constexpr int    BDIM   = 2700;
static constexpr int    NCODES = 1024;
static constexpr int    KP     = 2720;   // BDIM padded to 32 (85 K-steps for GEMM2)
static constexpr int    NPAD   = 2816;   // BDIM padded to 64 (44 col-blocks for GEMM1)
static constexpr size_t QST_N  = (size_t)M_ROWS * (size_t)BDIM;  // 22118400
static constexpr int    MAX_CAND = 32768;

typedef __bf16 bf16x8 __attribute__((ext_vector_type(8)));
typedef float  f32x4  __attribute__((ext_vector_type(4)));

// ---------------------------------------------------------------------------
// helpers
// ---------------------------------------------------------------------------
__device__ inline unsigned short bf16h(float x) {
    unsigned u = __float_as_uint(x);
    unsigned r = u + 0x7fffu + ((u >> 16) & 1u);
    return (unsigned short)(r >> 16);
}
__device__ inline float bf2f(unsigned short h) {
    return __uint_as_float(((unsigned)h) << 16);
}
__device__ inline void split2(float x, unsigned short& h, unsigned short& l) {
    h = bf16h(x);
    l = bf16h(x - bf2f(h));
}
__device__ inline void split3(float x, unsigned short& h, unsigned short& m,
                              unsigned short& l) {
    h = bf16h(x);
    const float r1 = x - bf2f(h);
    m = bf16h(r1);
    l = bf16h(r1 - bf2f(m));
}
__device__ inline unsigned long long pack_key(float v, int idx) {
    unsigned u = __float_as_uint(v);
    unsigned k = (u & 0x80000000u) ? ~u : (u | 0x80000000u);
    return ((unsigned long long)k << 32) | (unsigned)idx;
}
__device__ inline float unpack_val(unsigned long long key) {
    unsigned ku = (unsigned)(key >> 32);
    return (ku & 0x80000000u) ? __uint_as_float(ku & 0x7fffffffu)
                              : __uint_as_float(~ku);
}

// ---------------------------------------------------------------------------
// Fallback fp32 NT-GEMM (used only if ws is too small for the MFMA path)
// ---------------------------------------------------------------------------
template<int MODE>
__global__ __launch_bounds__(256, 2)
void gemm_nt(const float* __restrict__ A, const float* __restrict__ B,
             const float* __restrict__ bias,
             const float* __restrict__ rsq, const float* __restrict__ csq,
             float* __restrict__ C, int Ndim, int Kdim, int lda, int ldb, int ldc,
             unsigned short* __restrict__ zhi, unsigned short* __restrict__ zlo)
{
    constexpr int BK = 16;
    constexpr int LS = 132;
    __shared__ float As[2][BK][LS];
    __shared__ float Bs[2][BK][LS];

    const int tid  = threadIdx.x;
    const int row0 = blockIdx.y << 7;
    const int col0 = blockIdx.x << 7;
    const int sm = tid >> 2;
    const int sk = (tid & 3) << 2;
    const int wid  = tid >> 6;
    const int lane = tid & 63;
    const int tr = ((wid >> 1) << 6) | ((lane >> 3) << 3);
    const int tc = ((wid & 1) << 6) | ((lane & 7) << 3);

    float acc[8][8];
#pragma unroll
    for (int i = 0; i < 8; ++i)
#pragma unroll
        for (int j = 0; j < 8; ++j) acc[i][j] = 0.0f;

    const int nt = (Kdim + BK - 1) / BK;

    auto stage = [&](int t, int buf) {
        const int  kt    = t * BK;
        const bool kfull = (kt + BK) <= Kdim;
#pragma unroll
        for (int half = 0; half < 2; ++half) {
            const int m = sm + (half << 6);
            {
                const long long gr = row0 + m;
                const float* ap = A + gr * (long long)lda + kt + sk;
                float4 v;
                if (kfull) v = *reinterpret_cast<const float4*>(ap);
                else {
                    v.x = (kt + sk + 0 < Kdim) ? ap[0] : 0.0f;
                    v.y = (kt + sk + 1 < Kdim) ? ap[1] : 0.0f;
                    v.z = (kt + sk + 2 < Kdim) ? ap[2] : 0.0f;
                    v.w = (kt + sk + 3 < Kdim) ? ap[3] : 0.0f;
                }
                As[buf][sk + 0][m] = v.x; As[buf][sk + 1][m] = v.y;
                As[buf][sk + 2][m] = v.z; As[buf][sk + 3][m] = v.w;
            }
            {
                const long long gc = col0 + m;
                float4 v; v.x = v.y = v.z = v.w = 0.0f;
                if (gc < Ndim) {
                    const float* bp = B + gc * (long long)ldb + kt + sk;
                    if (kfull) v = *reinterpret_cast<const float4*>(bp);
                    else {
                        v.x = (kt + sk + 0 < Kdim) ? bp[0] : 0.0f;
                        v.y = (kt + sk + 1 < Kdim) ? bp[1] : 0.0f;
                        v.z = (kt + sk + 2 < Kdim) ? bp[2] : 0.0f;
                        v.w = (kt + sk + 3 < Kdim) ? bp[3] : 0.0f;
                    }
                }
                Bs[buf][sk + 0][m] = v.x; Bs[buf][sk + 1][m] = v.y;
                Bs[buf][sk + 2][m] = v.z; Bs[buf][sk + 3][m] = v.w;
            }
        }
    };

    stage(0, 0);
    __syncthreads();
    for (int t = 0; t < nt; ++t) {
        const int buf = t & 1;
        if (t + 1 < nt) stage(t + 1, buf ^ 1);
#pragma unroll
        for (int kk = 0; kk < BK; ++kk) {
            const float4 a0 = *reinterpret_cast<const float4*>(&As[buf][kk][tr]);
            const float4 a1 = *reinterpret_cast<const float4*>(&As[buf][kk][tr + 4]);
            const float4 b0 = *reinterpret_cast<const float4*>(&Bs[buf][kk][tc]);
            const float4 b1 = *reinterpret_cast<const float4*>(&Bs[buf][kk][tc + 4]);
            const float av[8] = {a0.x, a0.y, a0.z, a0.w, a1.x, a1.y, a1.z, a1.w};
            const float bv[8] = {b0.x, b0.y, b0.z, b0.w, b1.x, b1.y, b1.z, b1.w};
#pragma unroll
            for (int i = 0; i < 8; ++i)
#pragma unroll
                for (int j = 0; j < 8; ++j)
                    acc[i][j] = __builtin_fmaf(av[i], bv[j], acc[i][j]);
        }
        __syncthreads();
    }

#pragma unroll
    for (int i = 0; i < 8; ++i) {
        const long long gr = row0 + tr + i;
        float* crow = C + gr * (long long)ldc;
        float zr = 0.0f;
        if constexpr (MODE == 1) zr = rsq[gr];
#pragma unroll
        for (int jj = 0; jj < 8; jj += 4) {
            const int gc = col0 + tc + jj;
            if (gc + 4 <= Ndim) {
                float4 o;
                if constexpr (MODE == 0) {
                    const float4 bb = *reinterpret_cast<const float4*>(bias + gc);
                    o.x = acc[i][jj + 0] + bb.x;
                    o.y = acc[i][jj + 1] + bb.y;
                    o.z = acc[i][jj + 2] + bb.z;
                    o.w = acc[i][jj + 3] + bb.w;
                    if (zhi) {
                        ushort4 h, l;
                        split2(o.x, h.x, l.x); split2(o.y, h.y, l.y);
                        split2(o.z, h.z, l.z); split2(o.w, h.w, l.w);
                        *reinterpret_cast<ushort4*>(zhi + gr * (long long)KP + gc) = h;
                        *reinterpret_cast<ushort4*>(zlo + gr * (long long)KP + gc) = l;
                    }
                } else {
                    const float4 ee = *reinterpret_cast<const float4*>(csq + gc);
                    o.x = zr - 2.0f * acc[i][jj + 0] + ee.x;
                    o.y = zr - 2.0f * acc[i][jj + 1] + ee.y;
                    o.z = zr - 2.0f * acc[i][jj + 2] + ee.z;
                    o.w = zr - 2.0f * acc[i][jj + 3] + ee.w;
                }
                *reinterpret_cast<float4*>(crow + gc) = o;
            }
        }
    }
}

// ---------------------------------------------------------------------------
// GEMM1 (MFMA split-3): z[m,n] = sum_k slot[m,k]*W[n,k] + bias[n]
// slot = sh+sm+sl, W = Wh+Wm+Wl (bf16 digits). 6 products {hh,hM,Mh,hl,MM,lh}
// accumulate into ONE fp32 acc -> ~fp32 accuracy (per-term err ~2^-22).
// BM=128, BN=64, BK=32, 4 waves (2x2), double-buffered 72KB LDS (2 blk/CU).
// Epilogue: z -> Z (d_out), split2(z) -> zhi/zlo (KP stride), zsq via
// 16-lane shfl reduce + atomicAdd (zsq row-uniform error is argmin-invariant).
// ---------------------------------------------------------------------------
__global__ __launch_bounds__(256, 2)
void gemm1_mfma(const unsigned short* __restrict__ Ah_, const unsigned short* __restrict__ Am_,
                const unsigned short* __restrict__ Al_,
                const unsigned short* __restrict__ Bh_, const unsigned short* __restrict__ Bm_,
                const unsigned short* __restrict__ Bl_,
                const float* __restrict__ bias, float* __restrict__ Z,
                unsigned short* __restrict__ zhi, unsigned short* __restrict__ zlo,
                float* __restrict__ zsq)
{
    constexpr int NT = DMODEL / 32;           // 8 K-steps
    // per buffer: 3 A tiles [128][32] (4096 us) + 3 B tiles [64][32] (2048 us)
    __shared__ unsigned short lds[2][3 * 4096 + 3 * 2048];

    const int tid  = threadIdx.x;
    const int wid  = tid >> 6;
    const int lane = tid & 63;
    // XCD-aware swizzle: 2816 blocks = 8 * 352
    const int bid  = blockIdx.x;
    const int s    = (bid & 7) * 352 + (bid >> 3);
    const int row0 = (s & 63) << 7;           // 64 row-blocks of 128
    const int col0 = (s >> 6) << 6;           // 44 col-blocks of 64
    const int wr = wid >> 1, wc = wid & 1;

    f32x4 acc[4][2];
#pragma unroll
    for (int m = 0; m < 4; ++m)
#pragma unroll
        for (int n = 0; n < 2; ++n) acc[m][n] = (f32x4)0.0f;

    auto stage = [&](int t, int b) {
        const int kt = t * 32;
#pragma unroll
        for (int T = 0; T < 3; ++T) {         // A tiles: 128 rows, 8 chunks
            const unsigned short* src = (T == 0) ? Ah_ : (T == 1) ? Am_ : Al_;
#pragma unroll
            for (int q = 0; q < 2; ++q) {
                const int chunk = wid * 2 + q;
                const int r     = chunk * 16 + (lane >> 2);
                const int unswz = ((lane & 3) << 4) ^ ((r & 3) << 4);
                const unsigned short* g = src + (size_t)(row0 + r) * DMODEL + kt + (unswz >> 1);
                __builtin_amdgcn_global_load_lds(
                    (const __attribute__((address_space(1))) void*)g,
                    (__attribute__((address_space(3))) void*)(&lds[b][T * 4096 + chunk * 512]),
                    16, 0, 0);
            }
        }
#pragma unroll
        for (int T = 0; T < 3; ++T) {         // B tiles: 64 rows, 4 chunks
            const unsigned short* src = (T == 0) ? Bh_ : (T == 1) ? Bm_ : Bl_;
            const int chunk = wid;
            const int r     = chunk * 16 + (lane >> 2);
            const int unswz = ((lane & 3) << 4) ^ ((r & 3) << 4);
            const unsigned short* g = src + (size_t)(col0 + r) * DMODEL + kt + (unswz >> 1);
            __builtin_amdgcn_global_load_lds(
                (const __attribute__((address_space(1))) void*)g,
                (__attribute__((address_space(3))) void*)(&lds[b][12288 + T * 2048 + chunk * 512]),
                16, 0, 0);
        }
    };

    auto compute = [&](int b) {
        bf16x8 ah[4], am[4], al[4], bh[2], bm[2], bl[2];
        const int kb = (lane >> 4) << 4;
#pragma unroll
        for (int m = 0; m < 4; ++m) {
            const int r   = wr * 64 + m * 16 + (lane & 15);
            const int off = r * 32 + ((kb ^ ((r & 3) << 4)) >> 1);
            ah[m] = *reinterpret_cast<const bf16x8*>(&lds[b][off]);
            am[m] = *reinterpret_cast<const bf16x8*>(&lds[b][4096 + off]);
            al[m] = *reinterpret_cast<const bf16x8*>(&lds[b][8192 + off]);
        }
#pragma unroll
        for (int n = 0; n < 2; ++n) {
            const int r   = wc * 32 + n * 16 + (lane & 15);
            const int off = r * 32 + ((kb ^ ((r & 3) << 4)) >> 1);
            bh[n] = *reinterpret_cast<const bf16x8*>(&lds[b][12288 + off]);
            bm[n] = *reinterpret_cast<const bf16x8*>(&lds[b][14336 + off]);
            bl[n] = *reinterpret_cast<const bf16x8*>(&lds[b][16384 + off]);
        }
#pragma unroll
        for (int m = 0; m < 4; ++m)
#pragma unroll
            for (int n = 0; n < 2; ++n) {
                acc[m][n] = __builtin_amdgcn_mfma_f32_16x16x32_bf16(ah[m], bh[n], acc[m][n], 0, 0, 0);
                acc[m][n] = __builtin_amdgcn_mfma_f32_16x16x32_bf16(ah[m], bm[n], acc[m][n], 0, 0, 0);
                acc[m][n] = __builtin_amdgcn_mfma_f32_16x16x32_bf16(am[m], bh[n], acc[m][n], 0, 0, 0);
                acc[m][n] = __builtin_amdgcn_mfma_f32_16x16x32_bf16(ah[m], bl[n], acc[m][n], 0, 0, 0);
                acc[m][n] = __builtin_amdgcn_mfma_f32_16x16x32_bf16(am[m], bm[n], acc[m][n], 0, 0, 0);
                acc[m][n] = __builtin_amdgcn_mfma_f32_16x16x32_bf16(al[m], bh[n], acc[m][n], 0, 0, 0);
            }
    };

    stage(0, 0);
    __syncthreads();
    for (int t = 0; t < NT; ++t) {
        const int cur = t & 1;
        if (t + 1 < NT) stage(t + 1, cur ^ 1);
        compute(cur);
        __syncthreads();
    }

    // epilogue (C/D layout: col=lane&15, row=(lane>>4)*4+reg)
    float bv[2];
    int   cv[2];
#pragma unroll
    for (int n = 0; n < 2; ++n) {
        cv[n] = col0 + wc * 32 + n * 16 + (lane & 15);
        bv[n] = (cv[n] < BDIM) ? bias[cv[n]] : 0.0f;
    }
#pragma unroll
    for (int m = 0; m < 4; ++m) {
        const int gr0 = row0 + wr * 64 + m * 16 + ((lane >> 4) << 2);
#pragma unroll
        for (int r = 0; r < 4; ++r) {
            const int gr = gr0 + r;
            float s2 = 0.0f;
#pragma unroll
            for (int n = 0; n < 2; ++n) {
                if (cv[n] < BDIM) {
                    const float z = acc[m][n][r] + bv[n];
                    Z[(size_t)gr * BDIM + cv[n]] = z;
                    unsigned short h, l; split2(z, h, l);
                    zhi[(size_t)gr * KP + cv[n]] = h;
                    zlo[(size_t)gr * KP + cv[n]] = l;
                    s2 = __builtin_fmaf(z, z, s2);
                }
            }
            s2 += __shfl_xor(s2, 1);
            s2 += __shfl_xor(s2, 2);
            s2 += __shfl_xor(s2, 4);
            s2 += __shfl_xor(s2, 8);
            if ((lane & 15) == 0) atomicAdd(&zsq[gr], s2);
        }
    }
}

// ---------------------------------------------------------------------------
// GEMM2 (MFMA split-2): dist[m,n] = zsq[m] - 2*(z.e) + esq[n]
// 128x128, BK=32, 3 products (hh,hl,lh). In-row involution (r&3)<<4 on both
// the pre-swizzled global source and the ds_read offset (rule #21).
// ---------------------------------------------------------------------------
__global__ __launch_bounds__(256, 2)
void gemm2_mfma(const unsigned short* __restrict__ Ahi, const unsigned short* __restrict__ Alo,
                const unsigned short* __restrict__ Bhi, const unsigned short* __restrict__ Blo,
                const float* __restrict__ zsq, const float* __restrict__ esq,
                float* __restrict__ dist)
{
    constexpr int NT = KP / 32;   // 85
    __shared__ unsigned short lds[2][4][128 * 32];

    const int tid  = threadIdx.x;
    const int wid  = tid >> 6;
    const int lane = tid & 63;
    // XCD swizzle: 512 blocks, colb = bid&7 pins one 128-code strip per XCD L2
    const int bid  = blockIdx.x;
    const int row0 = (bid >> 3) << 7;
    const int col0 = (bid & 7) << 7;
    const int wr = wid >> 1, wc = wid & 1;

    f32x4 acc[4][4];
#pragma unroll
    for (int m = 0; m < 4; ++m)
#pragma unroll
        for (int n = 0; n < 4; ++n) acc[m][n] = (f32x4)0.0f;

    auto stage = [&](int t, int b) {
        const int kt = t * 32;
#pragma unroll
        for (int T = 0; T < 4; ++T) {
            const int base = (T < 2) ? row0 : col0;
            const unsigned short* src = (T == 0) ? Ahi : (T == 1) ? Alo : (T == 2) ? Bhi : Blo;
#pragma unroll
            for (int q = 0; q < 2; ++q) {
                const int chunk = wid * 2 + q;
                const int r     = chunk * 16 + (lane >> 2);
                const int unswz = ((lane & 3) << 4) ^ ((r & 3) << 4);
                const unsigned short* g = src + (size_t)(base + r) * KP + kt + (unswz >> 1);
                __builtin_amdgcn_global_load_lds(
                    (const __attribute__((address_space(1))) void*)g,
                    (__attribute__((address_space(3))) void*)(&lds[b][T][chunk * 512]),
                    16, 0, 0);
            }
        }
    };

    auto compute = [&](int b) {
        bf16x8 ah[4], al[4], bh[4], bl[4];
        const int kb = (lane >> 4) << 4;
#pragma unroll
        for (int m = 0; m < 4; ++m) {
            const int r   = wr * 64 + m * 16 + (lane & 15);
            const int off = r * 32 + ((kb ^ ((r & 3) << 4)) >> 1);
            ah[m] = *reinterpret_cast<const bf16x8*>(&lds[b][0][off]);
            al[m] = *reinterpret_cast<const bf16x8*>(&lds[b][1][off]);
        }
#pragma unroll
        for (int n = 0; n < 4; ++n) {
            const int r   = wc * 64 + n * 16 + (lane & 15);
            const int off = r * 32 + ((kb ^ ((r & 3) << 4)) >> 1);
            bh[n] = *reinterpret_cast<const bf16x8*>(&lds[b][2][off]);
            bl[n] = *reinterpret_cast<const bf16x8*>(&lds[b][3][off]);
        }
#pragma unroll
        for (int m = 0; m < 4; ++m)
#pragma unroll
            for (int n = 0; n < 4; ++n) {
                acc[m][n] = __builtin_amdgcn_mfma_f32_16x16x32_bf16(ah[m], bh[n], acc[m][n], 0, 0, 0);
                acc[m][n] = __builtin_amdgcn_mfma_f32_16x16x32_bf16(ah[m], bl[n], acc[m][n], 0, 0, 0);
                acc[m][n] = __builtin_amdgcn_mfma_f32_16x16x32_bf16(al[m], bh[n], acc[m][n], 0, 0, 0);
            }
    };

    stage(0, 0);
    __syncthreads();
    for (int t = 0; t < NT; ++t) {
        const int cur = t & 1;
        if (t + 1 < NT) stage(t + 1, cur ^ 1);
        compute(cur);
        __syncthreads();
    }

#pragma unroll
    for (int m = 0; m < 4; ++m) {
        const int gr0 = row0 + wr * 64 + m * 16 + ((lane >> 4) << 2);
#pragma unroll
        for (int n = 0; n < 4; ++n) {
            const int gc = col0 + wc * 64 + n * 16 + (lane & 15);
            const float eq = esq[gc];
#pragma unroll
            for (int r = 0; r < 4; ++r) {
                const int gr = gr0 + r;
                dist[(size_t)gr * NCODES + gc] = zsq[gr] - 2.0f * acc[m][n][r] + eq;
            }
        }
    }
}

// ---------------------------------------------------------------------------
// prep kernels
// ---------------------------------------------------------------------------
__global__ __launch_bounds__(256)
void esplit(const float* __restrict__ emb, unsigned short* __restrict__ ehi,
            unsigned short* __restrict__ elo)
{
    const int row = blockIdx.x;
    for (int g = threadIdx.x; g < KP / 4; g += 256) {
        const int c = g * 4;
        ushort4 h, l;
        if (c < BDIM) {
            const float4 v = *reinterpret_cast<const float4*>(emb + (size_t)row * BDIM + c);
            split2(v.x, h.x, l.x); split2(v.y, h.y, l.y);
            split2(v.z, h.z, l.z); split2(v.w, h.w, l.w);
        } else {
            h.x = h.y = h.z = h.w = 0; l = h;
        }
        *reinterpret_cast<ushort4*>(ehi + (size_t)row * KP + c) = h;
        *reinterpret_cast<ushort4*>(elo + (size_t)row * KP + c) = l;
    }
}

// slot [8192][256] -> 3 bf16 digit planes; one float4 per thread
__global__ __launch_bounds__(256)
void ssplit3(const float* __restrict__ slot, unsigned short* __restrict__ sh,
             unsigned short* __restrict__ sm, unsigned short* __restrict__ sl)
{
    const size_t i = (size_t)blockIdx.x * 256 + threadIdx.x;  // float4 index
    const float4 v = reinterpret_cast<const float4*>(slot)[i];
    ushort4 h, m, l;
    split3(v.x, h.x, m.x, l.x); split3(v.y, h.y, m.y, l.y);
    split3(v.z, h.z, m.z, l.z); split3(v.w, h.w, m.w, l.w);
    reinterpret_cast<ushort4*>(sh)[i] = h;
    reinterpret_cast<ushort4*>(sm)[i] = m;
    reinterpret_cast<ushort4*>(sl)[i] = l;
}

// W [2700][256] -> 3 digit planes padded to [2816][256] (pad rows zeroed)
__global__ __launch_bounds__(64)
void wsplit3(const float* __restrict__ W, unsigned short* __restrict__ wh,
             unsigned short* __restrict__ wm, unsigned short* __restrict__ wl)
{
    const int row = blockIdx.x;
    const int c   = threadIdx.x * 4;          // 64 threads x float4 = 256 cols
    ushort4 h, m, l;
    if (row < BDIM) {
        const float4 v = *reinterpret_cast<const float4*>(W + (size_t)row * DMODEL + c);
        split3(v.x, h.x, m.x, l.x); split3(v.y, h.y, m.y, l.y);
        split3(v.z, h.z, m.z, l.z); split3(v.w, h.w, m.w, l.w);
    } else {
        h.x = h.y = h.z = h.w = 0; m = h; l = h;
    }
    const size_t off = (size_t)row * DMODEL + c;
    *reinterpret_cast<ushort4*>(wh + off) = h;
    *reinterpret_cast<ushort4*>(wm + off) = m;
    *reinterpret_cast<ushort4*>(wl + off) = l;
}

__global__ void pad_z(unsigned short* __restrict__ zhi, unsigned short* __restrict__ zlo)
{
    const int i = blockIdx.x * 256 + threadIdx.x;
    if (i < M_ROWS * (KP - BDIM)) {
        const int r = i / (KP - BDIM);
        const int c = BDIM + i % (KP - BDIM);
        zhi[(size_t)r * KP + c] = 0;
        zlo[(size_t)r * KP + c] = 0;
    }
}

__global__ __launch_bounds__(256)
void rowsumsq(const float* __restrict__ src, float* __restrict__ out, int ncols)
{
    const int row = blockIdx.x;
    const float4* s = reinterpret_cast<const float4*>(src + (size_t)row * ncols);
    const int n4 = ncols >> 2;
    float acc = 0.0f;
    for (int i = threadIdx.x; i < n4; i += 256) {
        const float4 v = s[i];
        acc += v.x * v.x + v.y * v.y + v.z * v.z + v.w * v.w;
    }
    for (int off = 32; off; off >>= 1) acc += __shfl_down(acc, off);
    __shared__ float wsum[4];
    if ((threadIdx.x & 63) == 0) wsum[threadIdx.x >> 6] = acc;
    __syncthreads();
    if (threadIdx.x == 0) out[row] = wsum[0] + wsum[1] + wsum[2] + wsum[3];
}

// ---------------------------------------------------------------------------
// 8 rows per block: two-smallest argmin, softmax, prob/sse accumulation,
// candidate append for ambiguous rows (gap < DELTA).
// ---------------------------------------------------------------------------
static constexpr float DELTA = 0.25f;

__global__ __launch_bounds__(256)
void row_softmax8(const float* __restrict__ dist, float* __restrict__ prob_acc,
                  float* __restrict__ sse, float* __restrict__ out_idx_f,
                  int* __restrict__ out_idx_i, float* __restrict__ gap_out,
                  unsigned* __restrict__ cand, int* __restrict__ cand_count,
                  unsigned long long* __restrict__ row_best)
{
    const int tid = threadIdx.x;
    __shared__ unsigned long long wm0[4], wm1[4];
    __shared__ float wred[4];
    float pacc[4] = {0.f, 0.f, 0.f, 0.f};
    float sse_loc = 0.f;

    for (int rr = 0; rr < 8; ++rr) {
        const int row = blockIdx.x * 8 + rr;
        const float4 d4 = reinterpret_cast<const float4*>(dist + (size_t)row * NCODES)[tid];
        const float dv[4] = {d4.x, d4.y, d4.z, d4.w};

        unsigned long long b0 = 0xFFFFFFFFFFFFFFFFull, b1 = 0xFFFFFFFFFFFFFFFFull;
#pragma unroll
        for (int j = 0; j < 4; ++j) {
            const unsigned long long k = pack_key(dv[j], tid * 4 + j);
            if (k < b0) { b1 = b0; b0 = k; } else if (k < b1) { b1 = k; }
        }
        for (int off = 1; off < 64; off <<= 1) {
            const unsigned long long o0 = __shfl_xor(b0, off);
            const unsigned long long o1 = __shfl_xor(b1, off);
            const unsigned long long nb0 = (b0 < o0) ? b0 : o0;
            const unsigned long long mx  = (b0 < o0) ? o0 : b0;
            const unsigned long long mn1 = (b1 < o1) ? b1 : o1;
            b0 = nb0;
            b1 = (mx < mn1) ? mx : mn1;
        }
        __syncthreads();                       // protect reuse of wm/wred
        if ((tid & 63) == 0) { wm0[tid >> 6] = b0; wm1[tid >> 6] = b1; }
        __syncthreads();
        unsigned long long B0 = wm0[0], B1 = wm1[0];
#pragma unroll
        for (int w = 1; w < 4; ++w) {
            const unsigned long long o0 = wm0[w], o1 = wm1[w];
            const unsigned long long nb0 = (B0 < o0) ? B0 : o0;
            const unsigned long long mx  = (B0 < o0) ? o0 : B0;
            const unsigned long long mn1 = (B1 < o1) ? B1 : o1;
            B0 = nb0;
            B1 = (mx < mn1) ? mx : mn1;
        }
        const float m   = unpack_val(B0);
        const int   idx = (int)(B0 & 0xffffffffu);
        const float gap = unpack_val(B1) - m;

        if (gap < DELTA) {
            if (tid == 0) row_best[row] = 0xFFFFFFFFFFFFFFFFull;
#pragma unroll
            for (int j = 0; j < 4; ++j) {
                if (dv[j] - m < DELTA) {
                    const int slot = atomicAdd(cand_count, 1);
                    if (slot < MAX_CAND)
                        cand[slot] = ((unsigned)row << 10) | (unsigned)(tid * 4 + j);
                }
            }
        }

        float e[4];
        float s_local = 0.0f;
#pragma unroll
        for (int j = 0; j < 4; ++j) { e[j] = expf(m - dv[j]); s_local += e[j]; }
        for (int off = 32; off; off >>= 1) s_local += __shfl_down(s_local, off);
        if ((tid & 63) == 0) wred[tid >> 6] = s_local;
        __syncthreads();
        const float S = wred[0] + wred[1] + wred[2] + wred[3];
        const float inv = 1.0f / S;
#pragma unroll
        for (int j = 0; j < 4; ++j) pacc[j] += e[j] * inv;

        if (tid == 0) {
            out_idx_f[row] = (float)idx;
            out_idx_i[row] = idx;
            gap_out[row]   = gap;
            sse_loc += m;
        }
    }

    const float scale = 0.0001220703125f;      // 1/8192
#pragma unroll
    for (int j = 0; j < 4; ++j)
        if (pacc[j] > 0.0f) atomicAdd(&prob_acc[tid * 4 + j], pacc[j] * scale);
    if (tid == 0) atomicAdd(sse, sse_loc);
}

// ---------------------------------------------------------------------------
// Exact fp32 dist per candidate (one wave per (row,code) pair)
// ---------------------------------------------------------------------------
__global__ __launch_bounds__(256)
void refine2(const float* __restrict__ Zf, const float* __restrict__ emb,
             const unsigned* __restrict__ cand, const int* __restrict__ cand_count,
             const float* __restrict__ zsq, const float* __restrict__ esq,
             unsigned long long* __restrict__ row_best)
{
    const int nwaves = gridDim.x * 4;
    const int wglob  = blockIdx.x * 4 + (threadIdx.x >> 6);
    const int lane   = threadIdx.x & 63;
    const int n = min(*cand_count, MAX_CAND);
    for (int e = wglob; e < n; e += nwaves) {
        const unsigned pc  = cand[e];
        const int row  = (int)(pc >> 10);
        const int code = (int)(pc & 1023u);
        const float4* zp = reinterpret_cast<const float4*>(Zf + (size_t)row * BDIM);
        const float4* ep = reinterpret_cast<const float4*>(emb + (size_t)code * BDIM);
        float a0 = 0, a1 = 0, a2 = 0, a3 = 0;
        for (int k = lane; k < BDIM / 4; k += 64) {
            const float4 z4 = zp[k];
            const float4 e4 = ep[k];
            a0 = __builtin_fmaf(z4.x, e4.x, a0);
            a1 = __builtin_fmaf(z4.y, e4.y, a1);
            a2 = __builtin_fmaf(z4.z, e4.z, a2);
            a3 = __builtin_fmaf(z4.w, e4.w, a3);
        }
        float t = (a0 + a1) + (a2 + a3);
        for (int off = 32; off; off >>= 1) t += __shfl_down(t, off);
        if (lane == 0) {
            const float d = zsq[row] - 2.0f * t + esq[code];
            atomicMin(&row_best[row], pack_key(d, code));
        }
    }
}

__global__ __launch_bounds__(256)
void fixup(const float* __restrict__ gap, const unsigned long long* __restrict__ row_best,
           float* __restrict__ out_idx_f, int* __restrict__ out_idx_i)
{
    const int row = blockIdx.x * 256 + threadIdx.x;
    if (row < M_ROWS && gap[row] < DELTA) {
        const unsigned long long k = row_best[row];
        if (k != 0xFFFFFFFFFFFFFFFFull) {
            const int idx = (int)(k & 0xffffffffu);
            out_idx_f[row] = (float)idx;
            out_idx_i[row] = idx;
        }
    }
}

__global__ __launch_bounds__(256)
void gather_q(const float* __restrict__ embed, const int* __restrict__ idx,
              float* __restrict__ q)
{
    const int row  = blockIdx.x;
    const int code = idx[row];
    const float4* s = reinterpret_cast<const float4*>(embed + (size_t)code * BDIM);
    float4*       d = reinterpret_cast<float4*>(q + (size_t)row * BDIM);
    for (int i = threadIdx.x; i < (BDIM >> 2); i += 256) d[i] = s[i];
}

__global__ void init_ws(float* __restrict__ prob_acc, float* __restrict__ sse,
                        int* __restrict__ cand_count, float* __restrict__ zsq)
{
    const int i = blockIdx.x * 256 + threadIdx.x;
    if (i < NCODES) prob_acc[i] = 0.0f;
    if (i < M_ROWS) zsq[i] = 0.0f;
    if (i == 0) { sse[0] = 0.0f; cand_count[0] = 0; }
}

__global__ __launch_bounds__(256)
void finalize(const float* __restrict__ prob_acc, const float* __restrict__ sse,
              float* __restrict__ out)
{
    const int tid = threadIdx.x;
    float ent = 0.0f;
    for (int c = tid; c < NCODES; c += 256) {
        const float a = prob_acc[c];
        ent -= a * logf(a + 1e-8f);
    }
    for (int off = 32; off; off >>= 1) ent += __shfl_down(ent, off);
    __shared__ float wred[4];
    if ((tid & 63) == 0) wred[tid >> 6] = ent;
    __syncthreads();
    if (tid == 0) {
        out[QST_N + M_ROWS + 0] = sse[0] / 22118400.0f;
        out[QST_N + M_ROWS + 1] = wred[0] + wred[1] + wred[2] + wred[3];
    }
}

extern "C" void kernel_launch(void* const* d_in, const int* in_sizes, int n_in,
                              void* d_out, int out_size, void* d_ws, size_t ws_size,
                              hipStream_t stream)
{
    (void)in_sizes; (void)n_in; (void)out_size;
    const float* slot = (const float*)d_in[0];
    const float* W    = (const float*)d_in[1];
    const float* bpr  = (const float*)d_in[2];
    const float* emb  = (const float*)d_in[3];

    float* out  = (float*)d_out;
    float* Z    = out;              // z_e lives in the q_st region until gather
    float* idxf = out + QST_N;

    // ---- workspace layout ----
    const size_t DIST_B = (size_t)M_ROWS * NCODES * 4;          // 33,554,432
    const size_t ZSPL_B = (size_t)M_ROWS * KP * 2;              // 44,564,480
    const size_t ESPL_B = (size_t)NCODES * KP * 2;              //  5,570,560
    const size_t REQUIRED = DIST_B + 2 * ZSPL_B + 2 * ESPL_B + (1u << 20);
    const bool use_mfma = ws_size >= REQUIRED;

    char* w = (char*)d_ws;
    float* dist = (float*)w;                         w += DIST_B;
    // slot/W split-3 planes alias the dist region (dead before gemm2 writes it)
    const size_t SSPL_B = (size_t)M_ROWS * DMODEL * 2;          // 4,194,304
    const size_t WSPL_B = (size_t)NPAD   * DMODEL * 2;          // 1,441,792
    unsigned short* sh3 = (unsigned short*)(char*)dist;
    unsigned short* sm3 = (unsigned short*)((char*)dist + SSPL_B);
    unsigned short* sl3 = (unsigned short*)((char*)dist + 2 * SSPL_B);
    unsigned short* wh3 = (unsigned short*)((char*)dist + 3 * SSPL_B);
    unsigned short* wm3 = (unsigned short*)((char*)dist + 3 * SSPL_B + WSPL_B);
    unsigned short* wl3 = (unsigned short*)((char*)dist + 3 * SSPL_B + 2 * WSPL_B);

    unsigned short *zhi = nullptr, *zlo = nullptr, *ehi = nullptr, *elo = nullptr;
    if (use_mfma) {
        zhi = (unsigned short*)w;  w += ZSPL_B;
        zlo = (unsigned short*)w;  w += ZSPL_B;
        ehi = (unsigned short*)w;  w += ESPL_B;
        elo = (unsigned short*)w;  w += ESPL_B;
    }
    float* zsq  = (float*)w;                          w += (size_t)M_ROWS * 4;
    float* esq  = (float*)w;                          w += (size_t)NCODES * 4;
    float* gap  = (float*)w;                          w += (size_t)M_ROWS * 4;
    int*   idxi = (int*)w;                            w += (size_t)M_ROWS * 4;
    float* prob = (float*)w;                          w += (size_t)NCODES * 4;
    float* sse  = (float*)w;                          w += 256;
    unsigned long long* rbest = (unsigned long long*)w; w += (size_t)M_ROWS * 8;
    unsigned* cand = (unsigned*)w;                    w += (size_t)MAX_CAND * 4;
    int* ccount = (int*)w;

    init_ws<<<M_ROWS / 256, 256, 0, stream>>>(prob, sse, ccount, zsq);
    rowsumsq<<<NCODES, 256, 0, stream>>>(emb, esq, BDIM);

    if (use_mfma) {
        esplit<<<NCODES, 256, 0, stream>>>(emb, ehi, elo);
        ssplit3<<<(M_ROWS * DMODEL / 4) / 256, 256, 0, stream>>>(slot, sh3, sm3, sl3);
        wsplit3<<<NPAD, 64, 0, stream>>>(W, wh3, wm3, wl3);
        gemm1_mfma<<<(NPAD / 64) * (M_ROWS / 128), 256, 0, stream>>>(
            sh3, sm3, sl3, wh3, wm3, wl3, bpr, Z, zhi, zlo, zsq);
        pad_z<<<(M_ROWS * (KP - BDIM) + 255) / 256, 256, 0, stream>>>(zhi, zlo);
        gemm2_mfma<<<(NCODES / 128) * (M_ROWS / 128), 256, 0, stream>>>(
            zhi, zlo, ehi, elo, zsq, esq, dist);
    } else {
        gemm_nt<0><<<dim3((BDIM + 127) / 128, M_ROWS / 128), 256, 0, stream>>>(
            slot, W, bpr, nullptr, nullptr, Z, BDIM, DMODEL, DMODEL, DMODEL, BDIM,
            nullptr, nullptr);
        rowsumsq<<<M_ROWS, 256, 0, stream>>>(Z, zsq, BDIM);
        gemm_nt<1><<<dim3(NCODES / 128, M_ROWS / 128), 256, 0, stream>>>(
            Z, emb, nullptr, zsq, esq, dist, NCODES, BDIM, BDIM, BDIM, NCODES,
            nullptr, nullptr);
    }

    row_softmax8<<<M_ROWS / 8, 256, 0, stream>>>(dist, prob, sse, idxf, idxi, gap,
                                                 cand, ccount, rbest);
    refine2<<<128, 256, 0, stream>>>(Z, emb, cand, ccount, zsq, esq, rbest);
    fixup<<<M_ROWS / 256, 256, 0, stream>>>(gap, rbest, idxf, idxi);
    gather_q<<<M_ROWS, 256, 0, stream>>>(emb, idxi, Z);
    finalize<<<1, 256, 0, stream>>>(prob, sse, out);
}

// Round 6
// 408.955 us; speedup vs baseline: 2.5178x; 1.2048x over previous
//
#include <hip/hip_runtime.h>
#include <stdint.h>
#include <stddef.h>

// Problem geometry (fixed by setup_inputs)
static constexpr int    M_ROWS = 8192;   // B*K
static constexpr int    DMODEL = 256;
static constexpr int    BDIM   = 2700;
static constexpr int    NCODES = 1024;
static constexpr int    KP     = 2720;   // BDIM padded to 32 (85 K-steps for GEMM2)
static constexpr int    NPAD   = 2816;   // BDIM padded to 64 (44 col-blocks for GEMM1)
static constexpr size_t QST_N  = (size_t)M_ROWS * (size_t)BDIM;  // 22118400
static constexpr int    MAX_CAND = 32768;

typedef __bf16 bf16x8 __attribute__((ext_vector_type(8)));
typedef float  f32x4  __attribute__((ext_vector_type(4)));

// ---------------------------------------------------------------------------
// helpers
// ---------------------------------------------------------------------------
__device__ inline unsigned short bf16h(float x) {
    unsigned u = __float_as_uint(x);
    unsigned r = u + 0x7fffu + ((u >> 16) & 1u);
    return (unsigned short)(r >> 16);
}
__device__ inline float bf2f(unsigned short h) {
    return __uint_as_float(((unsigned)h) << 16);
}
__device__ inline void split3(float x, unsigned short& h, unsigned short& m,
                              unsigned short& l) {
    h = bf16h(x);
    const float r1 = x - bf2f(h);
    m = bf16h(r1);
    l = bf16h(r1 - bf2f(m));
}
__device__ inline unsigned long long pack_key(float v, int idx) {
    unsigned u = __float_as_uint(v);
    unsigned k = (u & 0x80000000u) ? ~u : (u | 0x80000000u);
    return ((unsigned long long)k << 32) | (unsigned)idx;
}
__device__ inline float unpack_val(unsigned long long key) {
    unsigned ku = (unsigned)(key >> 32);
    return (ku & 0x80000000u) ? __uint_as_float(ku & 0x7fffffffu)
                              : __uint_as_float(~ku);
}

// ---------------------------------------------------------------------------
// eprep: per code row -> esq, eh (bf16, K-padded); also zeroes zsq/prob/sse/cc.
// ---------------------------------------------------------------------------
__global__ __launch_bounds__(256)
void eprep(const float* __restrict__ emb, unsigned short* __restrict__ eh,
           float* __restrict__ esq, float* __restrict__ prob,
           float* __restrict__ sse, int* __restrict__ ccount,
           float* __restrict__ zsq)
{
    const int row = blockIdx.x;                 // 0..1023
    const int tid = threadIdx.x;
    if (tid < 8) zsq[row * 8 + tid] = 0.0f;     // 1024*8 = 8192
    if (tid == 0) prob[row] = 0.0f;
    if (row == 0 && tid == 0) { sse[0] = 0.0f; ccount[0] = 0; }

    float acc = 0.0f;
    for (int g = tid; g < KP / 4; g += 256) {
        const int c = g * 4;
        ushort4 h;
        if (c < BDIM) {
            const float4 v = *reinterpret_cast<const float4*>(emb + (size_t)row * BDIM + c);
            h.x = bf16h(v.x); h.y = bf16h(v.y); h.z = bf16h(v.z); h.w = bf16h(v.w);
            acc += v.x * v.x + v.y * v.y + v.z * v.z + v.w * v.w;
        } else {
            h.x = h.y = h.z = h.w = 0;
        }
        *reinterpret_cast<ushort4*>(eh + (size_t)row * KP + c) = h;
    }
    for (int off = 32; off; off >>= 1) acc += __shfl_down(acc, off);
    __shared__ float wsum[4];
    if ((tid & 63) == 0) wsum[tid >> 6] = acc;
    __syncthreads();
    if (tid == 0) esq[row] = wsum[0] + wsum[1] + wsum[2] + wsum[3];
}

// slot [8192][256] -> 3 bf16 digit planes; one float4 per thread
__global__ __launch_bounds__(256)
void ssplit3(const float* __restrict__ slot, unsigned short* __restrict__ sh,
             unsigned short* __restrict__ sm, unsigned short* __restrict__ sl)
{
    const size_t i = (size_t)blockIdx.x * 256 + threadIdx.x;  // float4 index
    const float4 v = reinterpret_cast<const float4*>(slot)[i];
    ushort4 h, m, l;
    split3(v.x, h.x, m.x, l.x); split3(v.y, h.y, m.y, l.y);
    split3(v.z, h.z, m.z, l.z); split3(v.w, h.w, m.w, l.w);
    reinterpret_cast<ushort4*>(sh)[i] = h;
    reinterpret_cast<ushort4*>(sm)[i] = m;
    reinterpret_cast<ushort4*>(sl)[i] = l;
}

// W [2700][256] -> 3 digit planes padded to [2816][256] (pad rows zeroed)
__global__ __launch_bounds__(64)
void wsplit3(const float* __restrict__ W, unsigned short* __restrict__ wh,
             unsigned short* __restrict__ wm, unsigned short* __restrict__ wl)
{
    const int row = blockIdx.x;
    const int c   = threadIdx.x * 4;
    ushort4 h, m, l;
    if (row < BDIM) {
        const float4 v = *reinterpret_cast<const float4*>(W + (size_t)row * DMODEL + c);
        split3(v.x, h.x, m.x, l.x); split3(v.y, h.y, m.y, l.y);
        split3(v.z, h.z, m.z, l.z); split3(v.w, h.w, m.w, l.w);
    } else {
        h.x = h.y = h.z = h.w = 0; m = h; l = h;
    }
    const size_t off = (size_t)row * DMODEL + c;
    *reinterpret_cast<ushort4*>(wh + off) = h;
    *reinterpret_cast<ushort4*>(wm + off) = m;
    *reinterpret_cast<ushort4*>(wl + off) = l;
}

// ---------------------------------------------------------------------------
// GEMM1 (MFMA split-3): z[m,n] = sum_k slot[m,k]*W[n,k] + bias[n]
// 6 products {hh,hm,mh,hl,mm,lh} into ONE fp32 acc -> ~fp32 accuracy.
// BM=128, BN=64, BK=32, 4 waves (2x2), double-buffered 72KB LDS.
// ROW-PINNED XCD swizzle: xcd=bid&7 owns row-blocks [8*xcd,8*xcd+8),
// iterating col-blocks fastest -> A panel (196KB) L2-resident across reuse.
// Epilogue: z -> Z (d_out), bf16(z) -> zh (KP stride, pad cols zeroed),
// zsq via 16-lane shfl reduce + atomicAdd (row-uniform err: argmin-safe).
// ---------------------------------------------------------------------------
__global__ __launch_bounds__(256, 2)
void gemm1_mfma(const unsigned short* __restrict__ Ah_, const unsigned short* __restrict__ Am_,
                const unsigned short* __restrict__ Al_,
                const unsigned short* __restrict__ Bh_, const unsigned short* __restrict__ Bm_,
                const unsigned short* __restrict__ Bl_,
                const float* __restrict__ bias, float* __restrict__ Z,
                unsigned short* __restrict__ zh, float* __restrict__ zsq)
{
    constexpr int NT = DMODEL / 32;           // 8 K-steps
    __shared__ unsigned short lds[2][3 * 4096 + 3 * 2048];

    const int tid  = threadIdx.x;
    const int wid  = tid >> 6;
    const int lane = tid & 63;
    // row-pinned XCD swizzle: grid 2816 = 8 XCD * (8 rowblk * 44 colblk)
    const int bid  = blockIdx.x;
    const int xcd  = bid & 7;
    const int q    = bid >> 3;                // 0..351
    const int row0 = (xcd * 8 + q / 44) << 7; // 64 row-blocks of 128
    const int col0 = (q % 44) << 6;           // 44 col-blocks of 64
    const int wr = wid >> 1, wc = wid & 1;

    f32x4 acc[4][2];
#pragma unroll
    for (int m = 0; m < 4; ++m)
#pragma unroll
        for (int n = 0; n < 2; ++n) acc[m][n] = (f32x4)0.0f;

    auto stage = [&](int t, int b) {
        const int kt = t * 32;
#pragma unroll
        for (int T = 0; T < 3; ++T) {         // A tiles: 128 rows, 8 chunks
            const unsigned short* src = (T == 0) ? Ah_ : (T == 1) ? Am_ : Al_;
#pragma unroll
            for (int qq = 0; qq < 2; ++qq) {
                const int chunk = wid * 2 + qq;
                const int r     = chunk * 16 + (lane >> 2);
                const int unswz = ((lane & 3) << 4) ^ ((r & 3) << 4);
                const unsigned short* g = src + (size_t)(row0 + r) * DMODEL + kt + (unswz >> 1);
                __builtin_amdgcn_global_load_lds(
                    (const __attribute__((address_space(1))) void*)g,
                    (__attribute__((address_space(3))) void*)(&lds[b][T * 4096 + chunk * 512]),
                    16, 0, 0);
            }
        }
#pragma unroll
        for (int T = 0; T < 3; ++T) {         // B tiles: 64 rows, 4 chunks
            const unsigned short* src = (T == 0) ? Bh_ : (T == 1) ? Bm_ : Bl_;
            const int chunk = wid;
            const int r     = chunk * 16 + (lane >> 2);
            const int unswz = ((lane & 3) << 4) ^ ((r & 3) << 4);
            const unsigned short* g = src + (size_t)(col0 + r) * DMODEL + kt + (unswz >> 1);
            __builtin_amdgcn_global_load_lds(
                (const __attribute__((address_space(1))) void*)g,
                (__attribute__((address_space(3))) void*)(&lds[b][12288 + T * 2048 + chunk * 512]),
                16, 0, 0);
        }
    };

    auto compute = [&](int b) {
        bf16x8 ah[4], am[4], al[4], bh[2], bm[2], bl[2];
        const int kb = (lane >> 4) << 4;
#pragma unroll
        for (int m = 0; m < 4; ++m) {
            const int r   = wr * 64 + m * 16 + (lane & 15);
            const int off = r * 32 + ((kb ^ ((r & 3) << 4)) >> 1);
            ah[m] = *reinterpret_cast<const bf16x8*>(&lds[b][off]);
            am[m] = *reinterpret_cast<const bf16x8*>(&lds[b][4096 + off]);
            al[m] = *reinterpret_cast<const bf16x8*>(&lds[b][8192 + off]);
        }
#pragma unroll
        for (int n = 0; n < 2; ++n) {
            const int r   = wc * 32 + n * 16 + (lane & 15);
            const int off = r * 32 + ((kb ^ ((r & 3) << 4)) >> 1);
            bh[n] = *reinterpret_cast<const bf16x8*>(&lds[b][12288 + off]);
            bm[n] = *reinterpret_cast<const bf16x8*>(&lds[b][14336 + off]);
            bl[n] = *reinterpret_cast<const bf16x8*>(&lds[b][16384 + off]);
        }
#pragma unroll
        for (int m = 0; m < 4; ++m)
#pragma unroll
            for (int n = 0; n < 2; ++n) {
                acc[m][n] = __builtin_amdgcn_mfma_f32_16x16x32_bf16(ah[m], bh[n], acc[m][n], 0, 0, 0);
                acc[m][n] = __builtin_amdgcn_mfma_f32_16x16x32_bf16(ah[m], bm[n], acc[m][n], 0, 0, 0);
                acc[m][n] = __builtin_amdgcn_mfma_f32_16x16x32_bf16(am[m], bh[n], acc[m][n], 0, 0, 0);
                acc[m][n] = __builtin_amdgcn_mfma_f32_16x16x32_bf16(ah[m], bl[n], acc[m][n], 0, 0, 0);
                acc[m][n] = __builtin_amdgcn_mfma_f32_16x16x32_bf16(am[m], bm[n], acc[m][n], 0, 0, 0);
                acc[m][n] = __builtin_amdgcn_mfma_f32_16x16x32_bf16(al[m], bh[n], acc[m][n], 0, 0, 0);
            }
    };

    stage(0, 0);
    __syncthreads();
    for (int t = 0; t < NT; ++t) {
        const int cur = t & 1;
        if (t + 1 < NT) stage(t + 1, cur ^ 1);
        compute(cur);
        __syncthreads();
    }

    // epilogue (C/D layout: col=lane&15, row=(lane>>4)*4+reg)
    float bv[2];
    int   cv[2];
#pragma unroll
    for (int n = 0; n < 2; ++n) {
        cv[n] = col0 + wc * 32 + n * 16 + (lane & 15);
        bv[n] = (cv[n] < BDIM) ? bias[cv[n]] : 0.0f;
    }
#pragma unroll
    for (int m = 0; m < 4; ++m) {
        const int gr0 = row0 + wr * 64 + m * 16 + ((lane >> 4) << 2);
#pragma unroll
        for (int r = 0; r < 4; ++r) {
            const int gr = gr0 + r;
            float s2 = 0.0f;
#pragma unroll
            for (int n = 0; n < 2; ++n) {
                if (cv[n] < BDIM) {
                    const float z = acc[m][n][r] + bv[n];
                    Z[(size_t)gr * BDIM + cv[n]] = z;
                    zh[(size_t)gr * KP + cv[n]] = bf16h(z);
                    s2 = __builtin_fmaf(z, z, s2);
                } else if (cv[n] < KP) {
                    zh[(size_t)gr * KP + cv[n]] = 0;   // K-pad columns
                }
            }
            s2 += __shfl_xor(s2, 1);
            s2 += __shfl_xor(s2, 2);
            s2 += __shfl_xor(s2, 4);
            s2 += __shfl_xor(s2, 8);
            if ((lane & 15) == 0) atomicAdd(&zsq[gr], s2);
        }
    }
}

// ---------------------------------------------------------------------------
// GEMM2 (single-plane bf16): dist[m,n] = zsq[m] - 2*(zh.eh) + esq[n]
// dist error sigma ~0.17, max ~0.94 -> DELTA=3.0 candidate window covers it;
// exact fp32 refine (on Z) guarantees the argmin. 128x128, BK=32, 16 MFMA/step.
// ---------------------------------------------------------------------------
__global__ __launch_bounds__(256, 2)
void gemm2_mfma(const unsigned short* __restrict__ Ah, const unsigned short* __restrict__ Bh,
                const float* __restrict__ zsq, const float* __restrict__ esq,
                float* __restrict__ dist)
{
    constexpr int NT = KP / 32;   // 85
    __shared__ unsigned short lds[2][2][128 * 32];

    const int tid  = threadIdx.x;
    const int wid  = tid >> 6;
    const int lane = tid & 63;
    // XCD swizzle: 512 blocks, colb = bid&7 pins one 128-code strip per XCD L2
    const int bid  = blockIdx.x;
    const int row0 = (bid >> 3) << 7;
    const int col0 = (bid & 7) << 7;
    const int wr = wid >> 1, wc = wid & 1;

    f32x4 acc[4][4];
#pragma unroll
    for (int m = 0; m < 4; ++m)
#pragma unroll
        for (int n = 0; n < 4; ++n) acc[m][n] = (f32x4)0.0f;

    auto stage = [&](int t, int b) {
        const int kt = t * 32;
#pragma unroll
        for (int T = 0; T < 2; ++T) {
            const int base = T ? col0 : row0;
            const unsigned short* src = T ? Bh : Ah;
#pragma unroll
            for (int q = 0; q < 2; ++q) {
                const int chunk = wid * 2 + q;
                const int r     = chunk * 16 + (lane >> 2);
                const int unswz = ((lane & 3) << 4) ^ ((r & 3) << 4);
                const unsigned short* g = src + (size_t)(base + r) * KP + kt + (unswz >> 1);
                __builtin_amdgcn_global_load_lds(
                    (const __attribute__((address_space(1))) void*)g,
                    (__attribute__((address_space(3))) void*)(&lds[b][T][chunk * 512]),
                    16, 0, 0);
            }
        }
    };

    auto compute = [&](int b) {
        bf16x8 ah[4], bh[4];
        const int kb = (lane >> 4) << 4;
#pragma unroll
        for (int m = 0; m < 4; ++m) {
            const int r   = wr * 64 + m * 16 + (lane & 15);
            const int off = r * 32 + ((kb ^ ((r & 3) << 4)) >> 1);
            ah[m] = *reinterpret_cast<const bf16x8*>(&lds[b][0][off]);
        }
#pragma unroll
        for (int n = 0; n < 4; ++n) {
            const int r   = wc * 64 + n * 16 + (lane & 15);
            const int off = r * 32 + ((kb ^ ((r & 3) << 4)) >> 1);
            bh[n] = *reinterpret_cast<const bf16x8*>(&lds[b][1][off]);
        }
#pragma unroll
        for (int m = 0; m < 4; ++m)
#pragma unroll
            for (int n = 0; n < 4; ++n)
                acc[m][n] = __builtin_amdgcn_mfma_f32_16x16x32_bf16(ah[m], bh[n], acc[m][n], 0, 0, 0);
    };

    stage(0, 0);
    __syncthreads();
    for (int t = 0; t < NT; ++t) {
        const int cur = t & 1;
        if (t + 1 < NT) stage(t + 1, cur ^ 1);
        compute(cur);
        __syncthreads();
    }

#pragma unroll
    for (int m = 0; m < 4; ++m) {
        const int gr0 = row0 + wr * 64 + m * 16 + ((lane >> 4) << 2);
#pragma unroll
        for (int n = 0; n < 4; ++n) {
            const int gc = col0 + wc * 64 + n * 16 + (lane & 15);
            const float eq = esq[gc];
#pragma unroll
            for (int r = 0; r < 4; ++r) {
                const int gr = gr0 + r;
                dist[(size_t)gr * NCODES + gc] = zsq[gr] - 2.0f * acc[m][n][r] + eq;
            }
        }
    }
}

// ---------------------------------------------------------------------------
// 32 rows per block: two-smallest argmin, softmax, prob/sse accumulation,
// candidate append for ambiguous rows (gap < DELTA).
// ---------------------------------------------------------------------------
static constexpr float DELTA = 3.0f;

__global__ __launch_bounds__(256)
void row_softmax32(const float* __restrict__ dist, float* __restrict__ prob_acc,
                   float* __restrict__ sse, float* __restrict__ out_idx_f,
                   int* __restrict__ out_idx_i, float* __restrict__ gap_out,
                   unsigned* __restrict__ cand, int* __restrict__ cand_count,
                   unsigned long long* __restrict__ row_best)
{
    const int tid = threadIdx.x;
    __shared__ unsigned long long wm0[4], wm1[4];
    __shared__ float wred[4];
    float pacc[4] = {0.f, 0.f, 0.f, 0.f};
    float sse_loc = 0.f;

    for (int rr = 0; rr < 32; ++rr) {
        const int row = blockIdx.x * 32 + rr;
        const float4 d4 = reinterpret_cast<const float4*>(dist + (size_t)row * NCODES)[tid];
        const float dv[4] = {d4.x, d4.y, d4.z, d4.w};

        unsigned long long b0 = 0xFFFFFFFFFFFFFFFFull, b1 = 0xFFFFFFFFFFFFFFFFull;
#pragma unroll
        for (int j = 0; j < 4; ++j) {
            const unsigned long long k = pack_key(dv[j], tid * 4 + j);
            if (k < b0) { b1 = b0; b0 = k; } else if (k < b1) { b1 = k; }
        }
        for (int off = 1; off < 64; off <<= 1) {
            const unsigned long long o0 = __shfl_xor(b0, off);
            const unsigned long long o1 = __shfl_xor(b1, off);
            const unsigned long long nb0 = (b0 < o0) ? b0 : o0;
            const unsigned long long mx  = (b0 < o0) ? o0 : b0;
            const unsigned long long mn1 = (b1 < o1) ? b1 : o1;
            b0 = nb0;
            b1 = (mx < mn1) ? mx : mn1;
        }
        __syncthreads();                       // protect reuse of wm/wred
        if ((tid & 63) == 0) { wm0[tid >> 6] = b0; wm1[tid >> 6] = b1; }
        __syncthreads();
        unsigned long long B0 = wm0[0], B1 = wm1[0];
#pragma unroll
        for (int w = 1; w < 4; ++w) {
            const unsigned long long o0 = wm0[w], o1 = wm1[w];
            const unsigned long long nb0 = (B0 < o0) ? B0 : o0;
            const unsigned long long mx  = (B0 < o0) ? o0 : B0;
            const unsigned long long mn1 = (B1 < o1) ? B1 : o1;
            B0 = nb0;
            B1 = (mx < mn1) ? mx : mn1;
        }
        const float m   = unpack_val(B0);
        const int   idx = (int)(B0 & 0xffffffffu);
        const float gap = unpack_val(B1) - m;

        if (gap < DELTA) {
            if (tid == 0) row_best[row] = 0xFFFFFFFFFFFFFFFFull;
#pragma unroll
            for (int j = 0; j < 4; ++j) {
                if (dv[j] - m < DELTA) {
                    const int slot = atomicAdd(cand_count, 1);
                    if (slot < MAX_CAND)
                        cand[slot] = ((unsigned)row << 10) | (unsigned)(tid * 4 + j);
                }
            }
        }

        float e[4];
        float s_local = 0.0f;
#pragma unroll
        for (int j = 0; j < 4; ++j) { e[j] = expf(m - dv[j]); s_local += e[j]; }
        for (int off = 32; off; off >>= 1) s_local += __shfl_down(s_local, off);
        if ((tid & 63) == 0) wred[tid >> 6] = s_local;
        __syncthreads();
        const float S = wred[0] + wred[1] + wred[2] + wred[3];
        const float inv = 1.0f / S;
#pragma unroll
        for (int j = 0; j < 4; ++j) pacc[j] += e[j] * inv;

        if (tid == 0) {
            out_idx_f[row] = (float)idx;
            out_idx_i[row] = idx;
            gap_out[row]   = gap;
            sse_loc += m;
        }
    }

    const float scale = 0.0001220703125f;      // 1/8192
#pragma unroll
    for (int j = 0; j < 4; ++j)
        if (pacc[j] > 0.0f) atomicAdd(&prob_acc[tid * 4 + j], pacc[j] * scale);
    if (tid == 0) atomicAdd(sse, sse_loc);
}

// ---------------------------------------------------------------------------
// Exact fp32 dist per candidate (one wave per (row,code) pair)
// ---------------------------------------------------------------------------
__global__ __launch_bounds__(256)
void refine2(const float* __restrict__ Zf, const float* __restrict__ emb,
             const unsigned* __restrict__ cand, const int* __restrict__ cand_count,
             const float* __restrict__ zsq, const float* __restrict__ esq,
             unsigned long long* __restrict__ row_best)
{
    const int nwaves = gridDim.x * 4;
    const int wglob  = blockIdx.x * 4 + (threadIdx.x >> 6);
    const int lane   = threadIdx.x & 63;
    const int n = min(*cand_count, MAX_CAND);
    for (int e = wglob; e < n; e += nwaves) {
        const unsigned pc  = cand[e];
        const int row  = (int)(pc >> 10);
        const int code = (int)(pc & 1023u);
        const float4* zp = reinterpret_cast<const float4*>(Zf + (size_t)row * BDIM);
        const float4* ep = reinterpret_cast<const float4*>(emb + (size_t)code * BDIM);
        float a0 = 0, a1 = 0, a2 = 0, a3 = 0;
        for (int k = lane; k < BDIM / 4; k += 64) {
            const float4 z4 = zp[k];
            const float4 e4 = ep[k];
            a0 = __builtin_fmaf(z4.x, e4.x, a0);
            a1 = __builtin_fmaf(z4.y, e4.y, a1);
            a2 = __builtin_fmaf(z4.z, e4.z, a2);
            a3 = __builtin_fmaf(z4.w, e4.w, a3);
        }
        float t = (a0 + a1) + (a2 + a3);
        for (int off = 32; off; off >>= 1) t += __shfl_down(t, off);
        if (lane == 0) {
            const float d = zsq[row] - 2.0f * t + esq[code];
            atomicMin(&row_best[row], pack_key(d, code));
        }
    }
}

// ---------------------------------------------------------------------------
// gather + fixup fused: refine ambiguous rows' index, then q_st = embed[idx]
// ---------------------------------------------------------------------------
__global__ __launch_bounds__(256)
void gather_fix(const float* __restrict__ embed, const float* __restrict__ gap,
                const unsigned long long* __restrict__ row_best,
                int* __restrict__ idxi, float* __restrict__ idxf,
                float* __restrict__ q)
{
    const int row = blockIdx.x;
    __shared__ int code_s;
    if (threadIdx.x == 0) {
        int code = idxi[row];
        if (gap[row] < DELTA) {
            const unsigned long long k = row_best[row];
            if (k != 0xFFFFFFFFFFFFFFFFull) {
                code = (int)(k & 0xffffffffu);
                idxi[row] = code;
                idxf[row] = (float)code;
            }
        }
        code_s = code;
    }
    __syncthreads();
    const int code = code_s;
    const float4* s = reinterpret_cast<const float4*>(embed + (size_t)code * BDIM);
    float4*       d = reinterpret_cast<float4*>(q + (size_t)row * BDIM);
    for (int i = threadIdx.x; i < (BDIM >> 2); i += 256) d[i] = s[i];
}

__global__ __launch_bounds__(256)
void finalize(const float* __restrict__ prob_acc, const float* __restrict__ sse,
              float* __restrict__ out)
{
    const int tid = threadIdx.x;
    float ent = 0.0f;
    for (int c = tid; c < NCODES; c += 256) {
        const float a = prob_acc[c];
        ent -= a * logf(a + 1e-8f);
    }
    for (int off = 32; off; off >>= 1) ent += __shfl_down(ent, off);
    __shared__ float wred[4];
    if ((tid & 63) == 0) wred[tid >> 6] = ent;
    __syncthreads();
    if (tid == 0) {
        out[QST_N + M_ROWS + 0] = sse[0] / 22118400.0f;
        out[QST_N + M_ROWS + 1] = wred[0] + wred[1] + wred[2] + wred[3];
    }
}

extern "C" void kernel_launch(void* const* d_in, const int* in_sizes, int n_in,
                              void* d_out, int out_size, void* d_ws, size_t ws_size,
                              hipStream_t stream)
{
    (void)in_sizes; (void)n_in; (void)out_size; (void)ws_size;
    const float* slot = (const float*)d_in[0];
    const float* W    = (const float*)d_in[1];
    const float* bpr  = (const float*)d_in[2];
    const float* emb  = (const float*)d_in[3];

    float* out  = (float*)d_out;
    float* Z    = out;              // z_e lives in the q_st region until gather
    float* idxf = out + QST_N;

    // ---- workspace layout (~84 MB; harness ws proven >= 129 MB) ----
    const size_t DIST_B = (size_t)M_ROWS * NCODES * 4;          // 33,554,432
    const size_t ZH_B   = (size_t)M_ROWS * KP * 2;              // 44,564,480
    const size_t EH_B   = (size_t)NCODES * KP * 2;              //  5,570,560

    char* w = (char*)d_ws;
    float* dist = (float*)w;                          w += DIST_B;
    // slot/W split-3 planes alias the dist region (dead before gemm2 writes it)
    const size_t SSPL_B = (size_t)M_ROWS * DMODEL * 2;          // 4,194,304
    const size_t WSPL_B = (size_t)NPAD   * DMODEL * 2;          // 1,441,792
    unsigned short* sh3 = (unsigned short*)(char*)dist;
    unsigned short* sm3 = (unsigned short*)((char*)dist + SSPL_B);
    unsigned short* sl3 = (unsigned short*)((char*)dist + 2 * SSPL_B);
    unsigned short* wh3 = (unsigned short*)((char*)dist + 3 * SSPL_B);
    unsigned short* wm3 = (unsigned short*)((char*)dist + 3 * SSPL_B + WSPL_B);
    unsigned short* wl3 = (unsigned short*)((char*)dist + 3 * SSPL_B + 2 * WSPL_B);

    unsigned short* zh = (unsigned short*)w;          w += ZH_B;
    unsigned short* eh = (unsigned short*)w;          w += EH_B;
    float* zsq  = (float*)w;                          w += (size_t)M_ROWS * 4;
    float* esq  = (float*)w;                          w += (size_t)NCODES * 4;
    float* gap  = (float*)w;                          w += (size_t)M_ROWS * 4;
    int*   idxi = (int*)w;                            w += (size_t)M_ROWS * 4;
    float* prob = (float*)w;                          w += (size_t)NCODES * 4;
    float* sse  = (float*)w;                          w += 256;
    unsigned long long* rbest = (unsigned long long*)w; w += (size_t)M_ROWS * 8;
    unsigned* cand = (unsigned*)w;                    w += (size_t)MAX_CAND * 4;
    int* ccount = (int*)w;

    eprep<<<NCODES, 256, 0, stream>>>(emb, eh, esq, prob, sse, ccount, zsq);
    ssplit3<<<(M_ROWS * DMODEL / 4) / 256, 256, 0, stream>>>(slot, sh3, sm3, sl3);
    wsplit3<<<NPAD, 64, 0, stream>>>(W, wh3, wm3, wl3);
    gemm1_mfma<<<(NPAD / 64) * (M_ROWS / 128), 256, 0, stream>>>(
        sh3, sm3, sl3, wh3, wm3, wl3, bpr, Z, zh, zsq);
    gemm2_mfma<<<(NCODES / 128) * (M_ROWS / 128), 256, 0, stream>>>(
        zh, eh, zsq, esq, dist);
    row_softmax32<<<M_ROWS / 32, 256, 0, stream>>>(dist, prob, sse, idxf, idxi, gap,
                                                   cand, ccount, rbest);
    refine2<<<256, 256, 0, stream>>>(Z, emb, cand, ccount, zsq, esq, rbest);
    gather_fix<<<M_ROWS, 256, 0, stream>>>(emb, gap, rbest, idxi, idxf, Z);
    finalize<<<1, 256, 0, stream>>>(prob, sse, out);
}

// Round 7
// 365.918 us; speedup vs baseline: 2.8139x; 1.1176x over previous
//
#include <hip/hip_runtime.h>
#include <stdint.h>
#include <stddef.h>

// Problem geometry (fixed by setup_inputs)
static constexpr int    M_ROWS = 8192;   // B*K
static constexpr int    DMODEL = 256;
static constexpr int    BDIM   = 2700;
static constexpr int    NCODES = 1024;
static constexpr int    KP     = 2720;   // BDIM padded to 32 (85 K-steps for GEMM2)
static constexpr int    NPAD   = 2816;   // BDIM padded to 64 (44 col-blocks for GEMM1)
static constexpr size_t QST_N  = (size_t)M_ROWS * (size_t)BDIM;  // 22118400
static constexpr int    MAX_CAND = 32768;

typedef __bf16 bf16x8 __attribute__((ext_vector_type(8)));
typedef float  f32x4  __attribute__((ext_vector_type(4)));

// ---------------------------------------------------------------------------
// helpers
// ---------------------------------------------------------------------------
__device__ inline unsigned short bf16h(float x) {
    unsigned u = __float_as_uint(x);
    unsigned r = u + 0x7fffu + ((u >> 16) & 1u);
    return (unsigned short)(r >> 16);
}
__device__ inline float bf2f(unsigned short h) {
    return __uint_as_float(((unsigned)h) << 16);
}
__device__ inline void split2(float x, unsigned short& h, unsigned short& l) {
    h = bf16h(x);
    l = bf16h(x - bf2f(h));
}
__device__ inline unsigned long long pack_key(float v, int idx) {
    unsigned u = __float_as_uint(v);
    unsigned k = (u & 0x80000000u) ? ~u : (u | 0x80000000u);
    return ((unsigned long long)k << 32) | (unsigned)idx;
}
__device__ inline float unpack_val(unsigned long long key) {
    unsigned ku = (unsigned)(key >> 32);
    return (ku & 0x80000000u) ? __uint_as_float(ku & 0x7fffffffu)
                              : __uint_as_float(~ku);
}

// ---------------------------------------------------------------------------
// prep (fused): blocks [0,1024): embed -> eh bf16 (K-padded) + esq, zero
// accumulators; [1024,1728): W -> 2 bf16 digit planes (row-padded to NPAD);
// [1728,3776): slot -> 2 bf16 digit planes.
// ---------------------------------------------------------------------------
__global__ __launch_bounds__(256)
void prep(const float* __restrict__ emb, const float* __restrict__ W,
          const float* __restrict__ slot,
          unsigned short* __restrict__ eh, float* __restrict__ esq,
          unsigned short* __restrict__ wh2, unsigned short* __restrict__ wm2,
          unsigned short* __restrict__ sh2, unsigned short* __restrict__ sl2,
          float* __restrict__ prob, float* __restrict__ sse,
          int* __restrict__ ccount, float* __restrict__ zsq)
{
    const int bid = blockIdx.x;
    const int tid = threadIdx.x;
    if (bid < NCODES) {
        // ---- embed prep ----
        const int row = bid;
        if (tid < 8) zsq[row * 8 + tid] = 0.0f;       // zero zsq[8192]
        if (tid == 0) prob[row] = 0.0f;
        if (row == 0 && tid == 0) { sse[0] = 0.0f; ccount[0] = 0; }
        float acc = 0.0f;
        for (int g = tid; g < KP / 4; g += 256) {
            const int c = g * 4;
            ushort4 h;
            if (c < BDIM) {
                const float4 v = *reinterpret_cast<const float4*>(emb + (size_t)row * BDIM + c);
                h.x = bf16h(v.x); h.y = bf16h(v.y); h.z = bf16h(v.z); h.w = bf16h(v.w);
                acc += v.x * v.x + v.y * v.y + v.z * v.z + v.w * v.w;
            } else {
                h.x = h.y = h.z = h.w = 0;
            }
            *reinterpret_cast<ushort4*>(eh + (size_t)row * KP + c) = h;
        }
        for (int off = 32; off; off >>= 1) acc += __shfl_down(acc, off);
        __shared__ float wsum[4];
        if ((tid & 63) == 0) wsum[tid >> 6] = acc;
        __syncthreads();
        if (tid == 0) esq[row] = wsum[0] + wsum[1] + wsum[2] + wsum[3];
    } else if (bid < NCODES + NPAD / 4) {
        // ---- W split-2, 4 rows per block ----
        const int row = (bid - NCODES) * 4 + (tid >> 6);
        const int c   = (tid & 63) * 4;
        ushort4 h, m;
        if (row < BDIM) {
            const float4 v = *reinterpret_cast<const float4*>(W + (size_t)row * DMODEL + c);
            split2(v.x, h.x, m.x); split2(v.y, h.y, m.y);
            split2(v.z, h.z, m.z); split2(v.w, h.w, m.w);
        } else {
            h.x = h.y = h.z = h.w = 0; m = h;
        }
        const size_t off = (size_t)row * DMODEL + c;
        *reinterpret_cast<ushort4*>(wh2 + off) = h;
        *reinterpret_cast<ushort4*>(wm2 + off) = m;
    } else {
        // ---- slot split-2, one float4 per thread ----
        const size_t i = (size_t)(bid - NCODES - NPAD / 4) * 256 + tid;
        const float4 v = reinterpret_cast<const float4*>(slot)[i];
        ushort4 h, l;
        split2(v.x, h.x, l.x); split2(v.y, h.y, l.y);
        split2(v.z, h.z, l.z); split2(v.w, h.w, l.w);
        reinterpret_cast<ushort4*>(sh2)[i] = h;
        reinterpret_cast<ushort4*>(sl2)[i] = l;
    }
}

// ---------------------------------------------------------------------------
// GEMM1 (MFMA, slot split-2 x W split-2 = 4 products into ONE fp32 acc):
// z[m,n] = sum_k slot[m,k]*W[n,k] + bias[n];  dz ~ 4e-6 (delta-s.W + s.delta-W)
// BM=128, BN=64, BK=32, 4 waves (2x2), double-buffered 48KB LDS -> 3 blk/CU.
// LDS swizzle: byte ^= ((r>>1)&3)<<4 -- conflict-free per 8-lane cycle
// (same involution pre-applied to global source; global_load_lds is linear).
// ROW-PINNED XCD swizzle: xcd=bid&7 owns row-blocks [8*xcd, 8*xcd+8).
// Epilogue: z -> Z (d_out), bf16(z) -> zh (KP stride), zsq via shfl+atomic.
// ---------------------------------------------------------------------------
__global__ __launch_bounds__(256, 3)
void gemm1_mfma(const unsigned short* __restrict__ Ah_, const unsigned short* __restrict__ Al_,
                const unsigned short* __restrict__ Bh_, const unsigned short* __restrict__ Bm_,
                const float* __restrict__ bias, float* __restrict__ Z,
                unsigned short* __restrict__ zh, float* __restrict__ zsq)
{
    constexpr int NT = DMODEL / 32;           // 8 K-steps
    // per buffer: 2 A tiles [128][32] (4096 us) + 2 B tiles [64][32] (2048 us)
    __shared__ unsigned short lds[2][2 * 4096 + 2 * 2048];

    const int tid  = threadIdx.x;
    const int wid  = tid >> 6;
    const int lane = tid & 63;
    // row-pinned XCD swizzle: grid 2816 = 8 XCD * (8 rowblk * 44 colblk)
    const int bid  = blockIdx.x;
    const int xcd  = bid & 7;
    const int q    = bid >> 3;                // 0..351
    const int row0 = (xcd * 8 + q / 44) << 7; // 64 row-blocks of 128
    const int col0 = (q % 44) << 6;           // 44 col-blocks of 64
    const int wr = wid >> 1, wc = wid & 1;

    f32x4 acc[4][2];
#pragma unroll
    for (int m = 0; m < 4; ++m)
#pragma unroll
        for (int n = 0; n < 2; ++n) acc[m][n] = (f32x4)0.0f;

    auto stage = [&](int t, int b) {
        const int kt = t * 32;
#pragma unroll
        for (int T = 0; T < 2; ++T) {         // A tiles: 128 rows, 8 chunks
            const unsigned short* src = T ? Al_ : Ah_;
#pragma unroll
            for (int qq = 0; qq < 2; ++qq) {
                const int chunk = wid * 2 + qq;
                const int r     = chunk * 16 + (lane >> 2);
                const int unswz = ((lane & 3) << 4) ^ (((r >> 1) & 3) << 4);
                const unsigned short* g = src + (size_t)(row0 + r) * DMODEL + kt + (unswz >> 1);
                __builtin_amdgcn_global_load_lds(
                    (const __attribute__((address_space(1))) void*)g,
                    (__attribute__((address_space(3))) void*)(&lds[b][T * 4096 + chunk * 512]),
                    16, 0, 0);
            }
        }
#pragma unroll
        for (int T = 0; T < 2; ++T) {         // B tiles: 64 rows, 4 chunks
            const unsigned short* src = T ? Bm_ : Bh_;
            const int chunk = wid;
            const int r     = chunk * 16 + (lane >> 2);
            const int unswz = ((lane & 3) << 4) ^ (((r >> 1) & 3) << 4);
            const unsigned short* g = src + (size_t)(col0 + r) * DMODEL + kt + (unswz >> 1);
            __builtin_amdgcn_global_load_lds(
                (const __attribute__((address_space(1))) void*)g,
                (__attribute__((address_space(3))) void*)(&lds[b][8192 + T * 2048 + chunk * 512]),
                16, 0, 0);
        }
    };

    auto compute = [&](int b) {
        bf16x8 a0[4], a1[4], b0[2], b1[2];
        const int kb = (lane >> 4) << 4;
#pragma unroll
        for (int m = 0; m < 4; ++m) {
            const int r   = wr * 64 + m * 16 + (lane & 15);
            const int off = r * 32 + ((kb ^ (((r >> 1) & 3) << 4)) >> 1);
            a0[m] = *reinterpret_cast<const bf16x8*>(&lds[b][off]);
            a1[m] = *reinterpret_cast<const bf16x8*>(&lds[b][4096 + off]);
        }
#pragma unroll
        for (int n = 0; n < 2; ++n) {
            const int r   = wc * 32 + n * 16 + (lane & 15);
            const int off = r * 32 + ((kb ^ (((r >> 1) & 3) << 4)) >> 1);
            b0[n] = *reinterpret_cast<const bf16x8*>(&lds[b][8192 + off]);
            b1[n] = *reinterpret_cast<const bf16x8*>(&lds[b][10240 + off]);
        }
#pragma unroll
        for (int m = 0; m < 4; ++m)
#pragma unroll
            for (int n = 0; n < 2; ++n) {
                acc[m][n] = __builtin_amdgcn_mfma_f32_16x16x32_bf16(a0[m], b0[n], acc[m][n], 0, 0, 0);
                acc[m][n] = __builtin_amdgcn_mfma_f32_16x16x32_bf16(a0[m], b1[n], acc[m][n], 0, 0, 0);
                acc[m][n] = __builtin_amdgcn_mfma_f32_16x16x32_bf16(a1[m], b0[n], acc[m][n], 0, 0, 0);
                acc[m][n] = __builtin_amdgcn_mfma_f32_16x16x32_bf16(a1[m], b1[n], acc[m][n], 0, 0, 0);
            }
    };

    stage(0, 0);
    __syncthreads();
    for (int t = 0; t < NT; ++t) {
        const int cur = t & 1;
        if (t + 1 < NT) stage(t + 1, cur ^ 1);
        compute(cur);
        __syncthreads();
    }

    // epilogue (C/D layout: col=lane&15, row=(lane>>4)*4+reg)
    float bv[2];
    int   cv[2];
#pragma unroll
    for (int n = 0; n < 2; ++n) {
        cv[n] = col0 + wc * 32 + n * 16 + (lane & 15);
        bv[n] = (cv[n] < BDIM) ? bias[cv[n]] : 0.0f;
    }
#pragma unroll
    for (int m = 0; m < 4; ++m) {
        const int gr0 = row0 + wr * 64 + m * 16 + ((lane >> 4) << 2);
#pragma unroll
        for (int r = 0; r < 4; ++r) {
            const int gr = gr0 + r;
            float s2 = 0.0f;
#pragma unroll
            for (int n = 0; n < 2; ++n) {
                if (cv[n] < BDIM) {
                    const float z = acc[m][n][r] + bv[n];
                    Z[(size_t)gr * BDIM + cv[n]] = z;
                    zh[(size_t)gr * KP + cv[n]] = bf16h(z);
                    s2 = __builtin_fmaf(z, z, s2);
                } else if (cv[n] < KP) {
                    zh[(size_t)gr * KP + cv[n]] = 0;   // K-pad columns
                }
            }
            s2 += __shfl_xor(s2, 1);
            s2 += __shfl_xor(s2, 2);
            s2 += __shfl_xor(s2, 4);
            s2 += __shfl_xor(s2, 8);
            if ((lane & 15) == 0) atomicAdd(&zsq[gr], s2);
        }
    }
}

// ---------------------------------------------------------------------------
// GEMM2 (single-plane bf16): dist[m,n] = zsq[m] - 2*(zh.eh) + esq[n]
// dist error sigma ~0.17 -> DELTA=3.0 candidate window + exact fp32 refine.
// 128x128, BK=32, 16 MFMA/step; conflict-free ((r>>1)&3) swizzle.
// ---------------------------------------------------------------------------
__global__ __launch_bounds__(256, 2)
void gemm2_mfma(const unsigned short* __restrict__ Ah, const unsigned short* __restrict__ Bh,
                const float* __restrict__ zsq, const float* __restrict__ esq,
                float* __restrict__ dist)
{
    constexpr int NT = KP / 32;   // 85
    __shared__ unsigned short lds[2][2][128 * 32];

    const int tid  = threadIdx.x;
    const int wid  = tid >> 6;
    const int lane = tid & 63;
    // XCD swizzle: 512 blocks, colb = bid&7 pins one 128-code strip per XCD L2
    const int bid  = blockIdx.x;
    const int row0 = (bid >> 3) << 7;
    const int col0 = (bid & 7) << 7;
    const int wr = wid >> 1, wc = wid & 1;

    f32x4 acc[4][4];
#pragma unroll
    for (int m = 0; m < 4; ++m)
#pragma unroll
        for (int n = 0; n < 4; ++n) acc[m][n] = (f32x4)0.0f;

    auto stage = [&](int t, int b) {
        const int kt = t * 32;
#pragma unroll
        for (int T = 0; T < 2; ++T) {
            const int base = T ? col0 : row0;
            const unsigned short* src = T ? Bh : Ah;
#pragma unroll
            for (int q = 0; q < 2; ++q) {
                const int chunk = wid * 2 + q;
                const int r     = chunk * 16 + (lane >> 2);
                const int unswz = ((lane & 3) << 4) ^ (((r >> 1) & 3) << 4);
                const unsigned short* g = src + (size_t)(base + r) * KP + kt + (unswz >> 1);
                __builtin_amdgcn_global_load_lds(
                    (const __attribute__((address_space(1))) void*)g,
                    (__attribute__((address_space(3))) void*)(&lds[b][T][chunk * 512]),
                    16, 0, 0);
            }
        }
    };

    auto compute = [&](int b) {
        bf16x8 ah[4], bh[4];
        const int kb = (lane >> 4) << 4;
#pragma unroll
        for (int m = 0; m < 4; ++m) {
            const int r   = wr * 64 + m * 16 + (lane & 15);
            const int off = r * 32 + ((kb ^ (((r >> 1) & 3) << 4)) >> 1);
            ah[m] = *reinterpret_cast<const bf16x8*>(&lds[b][0][off]);
        }
#pragma unroll
        for (int n = 0; n < 4; ++n) {
            const int r   = wc * 64 + n * 16 + (lane & 15);
            const int off = r * 32 + ((kb ^ (((r >> 1) & 3) << 4)) >> 1);
            bh[n] = *reinterpret_cast<const bf16x8*>(&lds[b][1][off]);
        }
#pragma unroll
        for (int m = 0; m < 4; ++m)
#pragma unroll
            for (int n = 0; n < 4; ++n)
                acc[m][n] = __builtin_amdgcn_mfma_f32_16x16x32_bf16(ah[m], bh[n], acc[m][n], 0, 0, 0);
    };

    stage(0, 0);
    __syncthreads();
    for (int t = 0; t < NT; ++t) {
        const int cur = t & 1;
        if (t + 1 < NT) stage(t + 1, cur ^ 1);
        compute(cur);
        __syncthreads();
    }

#pragma unroll
    for (int m = 0; m < 4; ++m) {
        const int gr0 = row0 + wr * 64 + m * 16 + ((lane >> 4) << 2);
#pragma unroll
        for (int n = 0; n < 4; ++n) {
            const int gc = col0 + wc * 64 + n * 16 + (lane & 15);
            const float eq = esq[gc];
#pragma unroll
            for (int r = 0; r < 4; ++r) {
                const int gr = gr0 + r;
                dist[(size_t)gr * NCODES + gc] = zsq[gr] - 2.0f * acc[m][n][r] + eq;
            }
        }
    }
}

// ---------------------------------------------------------------------------
// 32 rows per block: two-smallest argmin, softmax, prob/sse accumulation,
// candidate append for ambiguous rows (gap < DELTA).
// ---------------------------------------------------------------------------
static constexpr float DELTA = 3.0f;

__global__ __launch_bounds__(256)
void row_softmax32(const float* __restrict__ dist, float* __restrict__ prob_acc,
                   float* __restrict__ sse, float* __restrict__ out_idx_f,
                   int* __restrict__ out_idx_i, float* __restrict__ gap_out,
                   unsigned* __restrict__ cand, int* __restrict__ cand_count,
                   unsigned long long* __restrict__ row_best)
{
    const int tid = threadIdx.x;
    __shared__ unsigned long long wm0[4], wm1[4];
    __shared__ float wred[4];
    float pacc[4] = {0.f, 0.f, 0.f, 0.f};
    float sse_loc = 0.f;

    for (int rr = 0; rr < 32; ++rr) {
        const int row = blockIdx.x * 32 + rr;
        const float4 d4 = reinterpret_cast<const float4*>(dist + (size_t)row * NCODES)[tid];
        const float dv[4] = {d4.x, d4.y, d4.z, d4.w};

        unsigned long long b0 = 0xFFFFFFFFFFFFFFFFull, b1 = 0xFFFFFFFFFFFFFFFFull;
#pragma unroll
        for (int j = 0; j < 4; ++j) {
            const unsigned long long k = pack_key(dv[j], tid * 4 + j);
            if (k < b0) { b1 = b0; b0 = k; } else if (k < b1) { b1 = k; }
        }
        for (int off = 1; off < 64; off <<= 1) {
            const unsigned long long o0 = __shfl_xor(b0, off);
            const unsigned long long o1 = __shfl_xor(b1, off);
            const unsigned long long nb0 = (b0 < o0) ? b0 : o0;
            const unsigned long long mx  = (b0 < o0) ? o0 : b0;
            const unsigned long long mn1 = (b1 < o1) ? b1 : o1;
            b0 = nb0;
            b1 = (mx < mn1) ? mx : mn1;
        }
        __syncthreads();                       // protect reuse of wm/wred
        if ((tid & 63) == 0) { wm0[tid >> 6] = b0; wm1[tid >> 6] = b1; }
        __syncthreads();
        unsigned long long B0 = wm0[0], B1 = wm1[0];
#pragma unroll
        for (int w = 1; w < 4; ++w) {
            const unsigned long long o0 = wm0[w], o1 = wm1[w];
            const unsigned long long nb0 = (B0 < o0) ? B0 : o0;
            const unsigned long long mx  = (B0 < o0) ? o0 : B0;
            const unsigned long long mn1 = (B1 < o1) ? B1 : o1;
            B0 = nb0;
            B1 = (mx < mn1) ? mx : mn1;
        }
        const float m   = unpack_val(B0);
        const int   idx = (int)(B0 & 0xffffffffu);
        const float gap = unpack_val(B1) - m;

        if (gap < DELTA) {
            if (tid == 0) row_best[row] = 0xFFFFFFFFFFFFFFFFull;
#pragma unroll
            for (int j = 0; j < 4; ++j) {
                if (dv[j] - m < DELTA) {
                    const int slot = atomicAdd(cand_count, 1);
                    if (slot < MAX_CAND)
                        cand[slot] = ((unsigned)row << 10) | (unsigned)(tid * 4 + j);
                }
            }
        }

        float e[4];
        float s_local = 0.0f;
#pragma unroll
        for (int j = 0; j < 4; ++j) { e[j] = expf(m - dv[j]); s_local += e[j]; }
        for (int off = 32; off; off >>= 1) s_local += __shfl_down(s_local, off);
        if ((tid & 63) == 0) wred[tid >> 6] = s_local;
        __syncthreads();
        const float S = wred[0] + wred[1] + wred[2] + wred[3];
        const float inv = 1.0f / S;
#pragma unroll
        for (int j = 0; j < 4; ++j) pacc[j] += e[j] * inv;

        if (tid == 0) {
            out_idx_f[row] = (float)idx;
            out_idx_i[row] = idx;
            gap_out[row]   = gap;
            sse_loc += m;
        }
    }

    const float scale = 0.0001220703125f;      // 1/8192
#pragma unroll
    for (int j = 0; j < 4; ++j)
        if (pacc[j] > 0.0f) atomicAdd(&prob_acc[tid * 4 + j], pacc[j] * scale);
    if (tid == 0) atomicAdd(sse, sse_loc);
}

// ---------------------------------------------------------------------------
// Exact fp32 dist per candidate (one wave per (row,code) pair)
// ---------------------------------------------------------------------------
__global__ __launch_bounds__(256)
void refine2(const float* __restrict__ Zf, const float* __restrict__ emb,
             const unsigned* __restrict__ cand, const int* __restrict__ cand_count,
             const float* __restrict__ zsq, const float* __restrict__ esq,
             unsigned long long* __restrict__ row_best)
{
    const int nwaves = gridDim.x * 4;
    const int wglob  = blockIdx.x * 4 + (threadIdx.x >> 6);
    const int lane   = threadIdx.x & 63;
    const int n = min(*cand_count, MAX_CAND);
    for (int e = wglob; e < n; e += nwaves) {
        const unsigned pc  = cand[e];
        const int row  = (int)(pc >> 10);
        const int code = (int)(pc & 1023u);
        const float4* zp = reinterpret_cast<const float4*>(Zf + (size_t)row * BDIM);
        const float4* ep = reinterpret_cast<const float4*>(emb + (size_t)code * BDIM);
        float a0 = 0, a1 = 0, a2 = 0, a3 = 0;
        for (int k = lane; k < BDIM / 4; k += 64) {
            const float4 z4 = zp[k];
            const float4 e4 = ep[k];
            a0 = __builtin_fmaf(z4.x, e4.x, a0);
            a1 = __builtin_fmaf(z4.y, e4.y, a1);
            a2 = __builtin_fmaf(z4.z, e4.z, a2);
            a3 = __builtin_fmaf(z4.w, e4.w, a3);
        }
        float t = (a0 + a1) + (a2 + a3);
        for (int off = 32; off; off >>= 1) t += __shfl_down(t, off);
        if (lane == 0) {
            const float d = zsq[row] - 2.0f * t + esq[code];
            atomicMin(&row_best[row], pack_key(d, code));
        }
    }
}

// ---------------------------------------------------------------------------
// gather + fixup fused: refine ambiguous rows' index, then q_st = embed[idx]
// ---------------------------------------------------------------------------
__global__ __launch_bounds__(256)
void gather_fix(const float* __restrict__ embed, const float* __restrict__ gap,
                const unsigned long long* __restrict__ row_best,
                int* __restrict__ idxi, float* __restrict__ idxf,
                float* __restrict__ q)
{
    const int row = blockIdx.x;
    __shared__ int code_s;
    if (threadIdx.x == 0) {
        int code = idxi[row];
        if (gap[row] < DELTA) {
            const unsigned long long k = row_best[row];
            if (k != 0xFFFFFFFFFFFFFFFFull) {
                code = (int)(k & 0xffffffffu);
                idxi[row] = code;
                idxf[row] = (float)code;
            }
        }
        code_s = code;
    }
    __syncthreads();
    const int code = code_s;
    const float4* s = reinterpret_cast<const float4*>(embed + (size_t)code * BDIM);
    float4*       d = reinterpret_cast<float4*>(q + (size_t)row * BDIM);
    for (int i = threadIdx.x; i < (BDIM >> 2); i += 256) d[i] = s[i];
}

__global__ __launch_bounds__(256)
void finalize(const float* __restrict__ prob_acc, const float* __restrict__ sse,
              float* __restrict__ out)
{
    const int tid = threadIdx.x;
    float ent = 0.0f;
    for (int c = tid; c < NCODES; c += 256) {
        const float a = prob_acc[c];
        ent -= a * logf(a + 1e-8f);
    }
    for (int off = 32; off; off >>= 1) ent += __shfl_down(ent, off);
    __shared__ float wred[4];
    if ((tid & 63) == 0) wred[tid >> 6] = ent;
    __syncthreads();
    if (tid == 0) {
        out[QST_N + M_ROWS + 0] = sse[0] / 22118400.0f;
        out[QST_N + M_ROWS + 1] = wred[0] + wred[1] + wred[2] + wred[3];
    }
}

extern "C" void kernel_launch(void* const* d_in, const int* in_sizes, int n_in,
                              void* d_out, int out_size, void* d_ws, size_t ws_size,
                              hipStream_t stream)
{
    (void)in_sizes; (void)n_in; (void)out_size; (void)ws_size;
    const float* slot = (const float*)d_in[0];
    const float* W    = (const float*)d_in[1];
    const float* bpr  = (const float*)d_in[2];
    const float* emb  = (const float*)d_in[3];

    float* out  = (float*)d_out;
    float* Z    = out;              // z_e lives in the q_st region until gather
    float* idxf = out + QST_N;

    // ---- workspace layout (~84 MB; ws proven >= 129 MB in rounds 3-6) ----
    const size_t DIST_B = (size_t)M_ROWS * NCODES * 4;          // 33,554,432
    const size_t ZH_B   = (size_t)M_ROWS * KP * 2;              // 44,564,480
    const size_t EH_B   = (size_t)NCODES * KP * 2;              //  5,570,560

    char* w = (char*)d_ws;
    float* dist = (float*)w;                          w += DIST_B;
    // slot/W split-2 planes alias the dist region (dead before gemm2 writes it)
    unsigned short* sh2 = (unsigned short*)dist;
    unsigned short* sl2 = sh2 + (size_t)M_ROWS * DMODEL;
    unsigned short* wh2 = sl2 + (size_t)M_ROWS * DMODEL;
    unsigned short* wm2 = wh2 + (size_t)NPAD * DMODEL;

    unsigned short* zh = (unsigned short*)w;          w += ZH_B;
    unsigned short* eh = (unsigned short*)w;          w += EH_B;
    float* zsq  = (float*)w;                          w += (size_t)M_ROWS * 4;
    float* esq  = (float*)w;                          w += (size_t)NCODES * 4;
    float* gap  = (float*)w;                          w += (size_t)M_ROWS * 4;
    int*   idxi = (int*)w;                            w += (size_t)M_ROWS * 4;
    float* prob = (float*)w;                          w += (size_t)NCODES * 4;
    float* sse  = (float*)w;                          w += 256;
    unsigned long long* rbest = (unsigned long long*)w; w += (size_t)M_ROWS * 8;
    unsigned* cand = (unsigned*)w;                    w += (size_t)MAX_CAND * 4;
    int* ccount = (int*)w;

    // fused prep: 1024 embed blocks + 704 W blocks + 2048 slot blocks
    prep<<<NCODES + NPAD / 4 + (M_ROWS * DMODEL / 4) / 256, 256, 0, stream>>>(
        emb, W, slot, eh, esq, wh2, wm2, sh2, sl2, prob, sse, ccount, zsq);
    gemm1_mfma<<<(NPAD / 64) * (M_ROWS / 128), 256, 0, stream>>>(
        sh2, sl2, wh2, wm2, bpr, Z, zh, zsq);
    gemm2_mfma<<<(NCODES / 128) * (M_ROWS / 128), 256, 0, stream>>>(
        zh, eh, zsq, esq, dist);
    row_softmax32<<<M_ROWS / 32, 256, 0, stream>>>(dist, prob, sse, idxf, idxi, gap,
                                                   cand, ccount, rbest);
    refine2<<<256, 256, 0, stream>>>(Z, emb, cand, ccount, zsq, esq, rbest);
    gather_fix<<<M_ROWS, 256, 0, stream>>>(emb, gap, rbest, idxi, idxf, Z);
    finalize<<<1, 256, 0, stream>>>(prob, sse, out);
}

// Round 8
// 365.824 us; speedup vs baseline: 2.8146x; 1.0003x over previous
//
#include <hip/hip_runtime.h>
#include <stdint.h>
#include <stddef.h>

// Problem geometry (fixed by setup_inputs)
static constexpr int    M_ROWS = 8192;   // B*K
static constexpr int    DMODEL = 256;
static constexpr int    BDIM   = 2700;
static constexpr int    NCODES = 1024;
static constexpr int    KP     = 2720;   // BDIM padded to 32 (85 K-steps for GEMM2)
static constexpr int    NPAD   = 2816;   // BDIM padded to 128 (22 col-blocks for GEMM1)
static constexpr size_t QST_N  = (size_t)M_ROWS * (size_t)BDIM;  // 22118400
static constexpr int    MAX_CAND = 32768;

typedef __bf16 bf16x8 __attribute__((ext_vector_type(8)));
typedef float  f32x4  __attribute__((ext_vector_type(4)));

// ---------------------------------------------------------------------------
// helpers
// ---------------------------------------------------------------------------
__device__ inline unsigned short bf16h(float x) {
    unsigned u = __float_as_uint(x);
    unsigned r = u + 0x7fffu + ((u >> 16) & 1u);
    return (unsigned short)(r >> 16);
}
__device__ inline float bf2f(unsigned short h) {
    return __uint_as_float(((unsigned)h) << 16);
}
__device__ inline void split2(float x, unsigned short& h, unsigned short& l) {
    h = bf16h(x);
    l = bf16h(x - bf2f(h));
}
__device__ inline unsigned long long pack_key(float v, int idx) {
    unsigned u = __float_as_uint(v);
    unsigned k = (u & 0x80000000u) ? ~u : (u | 0x80000000u);
    return ((unsigned long long)k << 32) | (unsigned)idx;
}
__device__ inline float unpack_val(unsigned long long key) {
    unsigned ku = (unsigned)(key >> 32);
    return (ku & 0x80000000u) ? __uint_as_float(ku & 0x7fffffffu)
                              : __uint_as_float(~ku);
}

// ---------------------------------------------------------------------------
// prep (fused): blocks [0,1024): embed -> eh bf16 (K-padded) + esq, zero
// accumulators; [1024,1728): W -> 2 bf16 digit planes (row-padded to NPAD);
// [1728,3776): slot -> 2 bf16 digit planes.
// ---------------------------------------------------------------------------
__global__ __launch_bounds__(256)
void prep(const float* __restrict__ emb, const float* __restrict__ W,
          const float* __restrict__ slot,
          unsigned short* __restrict__ eh, float* __restrict__ esq,
          unsigned short* __restrict__ wh2, unsigned short* __restrict__ wm2,
          unsigned short* __restrict__ sh2, unsigned short* __restrict__ sl2,
          float* __restrict__ prob, float* __restrict__ sse,
          int* __restrict__ ccount, float* __restrict__ zsq)
{
    const int bid = blockIdx.x;
    const int tid = threadIdx.x;
    if (bid < NCODES) {
        // ---- embed prep ----
        const int row = bid;
        if (tid < 8) zsq[row * 8 + tid] = 0.0f;       // zero zsq[8192]
        if (tid == 0) prob[row] = 0.0f;
        if (row == 0 && tid == 0) { sse[0] = 0.0f; ccount[0] = 0; }
        float acc = 0.0f;
        for (int g = tid; g < KP / 4; g += 256) {
            const int c = g * 4;
            ushort4 h;
            if (c < BDIM) {
                const float4 v = *reinterpret_cast<const float4*>(emb + (size_t)row * BDIM + c);
                h.x = bf16h(v.x); h.y = bf16h(v.y); h.z = bf16h(v.z); h.w = bf16h(v.w);
                acc += v.x * v.x + v.y * v.y + v.z * v.z + v.w * v.w;
            } else {
                h.x = h.y = h.z = h.w = 0;
            }
            *reinterpret_cast<ushort4*>(eh + (size_t)row * KP + c) = h;
        }
        for (int off = 32; off; off >>= 1) acc += __shfl_down(acc, off);
        __shared__ float wsum[4];
        if ((tid & 63) == 0) wsum[tid >> 6] = acc;
        __syncthreads();
        if (tid == 0) esq[row] = wsum[0] + wsum[1] + wsum[2] + wsum[3];
    } else if (bid < NCODES + NPAD / 4) {
        // ---- W split-2, 4 rows per block ----
        const int row = (bid - NCODES) * 4 + (tid >> 6);
        const int c   = (tid & 63) * 4;
        ushort4 h, m;
        if (row < BDIM) {
            const float4 v = *reinterpret_cast<const float4*>(W + (size_t)row * DMODEL + c);
            split2(v.x, h.x, m.x); split2(v.y, h.y, m.y);
            split2(v.z, h.z, m.z); split2(v.w, h.w, m.w);
        } else {
            h.x = h.y = h.z = h.w = 0; m = h;
        }
        const size_t off = (size_t)row * DMODEL + c;
        *reinterpret_cast<ushort4*>(wh2 + off) = h;
        *reinterpret_cast<ushort4*>(wm2 + off) = m;
    } else {
        // ---- slot split-2, one float4 per thread ----
        const size_t i = (size_t)(bid - NCODES - NPAD / 4) * 256 + tid;
        const float4 v = reinterpret_cast<const float4*>(slot)[i];
        ushort4 h, l;
        split2(v.x, h.x, l.x); split2(v.y, h.y, l.y);
        split2(v.z, h.z, l.z); split2(v.w, h.w, l.w);
        reinterpret_cast<ushort4*>(sh2)[i] = h;
        reinterpret_cast<ushort4*>(sl2)[i] = l;
    }
}

// ---------------------------------------------------------------------------
// GEMM1 (MFMA, slot split-2 x W split-2 = 4 products into ONE fp32 acc):
// z[m,n] = sum_k slot[m,k]*W[n,k] + bias[n]
// BM=128, BN=128, BK=32, 4 waves (2x2, 64x64 each), dbuf 64KB LDS, 2 blk/CU.
// 64 MFMA-instr per wave per K-step (2x prev round -> better barrier amortize).
// LDS swizzle byte ^= ((r>>1)&3)<<4, conflict-free; same involution applied
// to the pre-swizzled global source (global_load_lds writes linearly).
// ROW-PINNED XCD swizzle: grid 1408 = 8 XCD * (8 rowblk * 22 colblk).
// Epilogue: z -> Z (d_out), bf16(z) -> zh (KP stride), zsq via shfl+atomic.
// ---------------------------------------------------------------------------
__global__ __launch_bounds__(256, 2)
void gemm1_mfma(const unsigned short* __restrict__ Ah_, const unsigned short* __restrict__ Al_,
                const unsigned short* __restrict__ Bh_, const unsigned short* __restrict__ Bm_,
                const float* __restrict__ bias, float* __restrict__ Z,
                unsigned short* __restrict__ zh, float* __restrict__ zsq)
{
    constexpr int NT = DMODEL / 32;           // 8 K-steps
    // per buffer: A planes at 0,4096; B planes at 8192,12288 (ushort units)
    __shared__ unsigned short lds[2][16384];

    const int tid  = threadIdx.x;
    const int wid  = tid >> 6;
    const int lane = tid & 63;
    const int bid  = blockIdx.x;
    const int xcd  = bid & 7;
    const int q    = bid >> 3;                // 0..175
    const int row0 = (xcd * 8 + q / 22) << 7; // 64 row-blocks of 128
    const int col0 = (q % 22) << 7;           // 22 col-blocks of 128
    const int wr = wid >> 1, wc = wid & 1;

    f32x4 acc[4][4];
#pragma unroll
    for (int m = 0; m < 4; ++m)
#pragma unroll
        for (int n = 0; n < 4; ++n) acc[m][n] = (f32x4)0.0f;

    auto stage = [&](int t, int b) {
        const int kt = t * 32;
#pragma unroll
        for (int T = 0; T < 4; ++T) {         // 0:Ah 1:Al 2:Bh 3:Bm, 128 rows each
            const unsigned short* src = (T == 0) ? Ah_ : (T == 1) ? Al_ :
                                        (T == 2) ? Bh_ : Bm_;
            const int base = (T < 2) ? row0 : col0;
#pragma unroll
            for (int qq = 0; qq < 2; ++qq) {
                const int chunk = wid * 2 + qq;
                const int r     = chunk * 16 + (lane >> 2);
                const int unswz = ((lane & 3) << 4) ^ (((r >> 1) & 3) << 4);
                const unsigned short* g = src + (size_t)(base + r) * DMODEL + kt + (unswz >> 1);
                __builtin_amdgcn_global_load_lds(
                    (const __attribute__((address_space(1))) void*)g,
                    (__attribute__((address_space(3))) void*)(&lds[b][T * 4096 + chunk * 512]),
                    16, 0, 0);
            }
        }
    };

    auto compute = [&](int b) {
        bf16x8 a0[4], a1[4], b0[4], b1[4];
        const int kb = (lane >> 4) << 4;
#pragma unroll
        for (int m = 0; m < 4; ++m) {
            const int r   = wr * 64 + m * 16 + (lane & 15);
            const int off = r * 32 + ((kb ^ (((r >> 1) & 3) << 4)) >> 1);
            a0[m] = *reinterpret_cast<const bf16x8*>(&lds[b][off]);
            a1[m] = *reinterpret_cast<const bf16x8*>(&lds[b][4096 + off]);
        }
#pragma unroll
        for (int n = 0; n < 4; ++n) {
            const int r   = wc * 64 + n * 16 + (lane & 15);
            const int off = r * 32 + ((kb ^ (((r >> 1) & 3) << 4)) >> 1);
            b0[n] = *reinterpret_cast<const bf16x8*>(&lds[b][8192 + off]);
            b1[n] = *reinterpret_cast<const bf16x8*>(&lds[b][12288 + off]);
        }
#pragma unroll
        for (int m = 0; m < 4; ++m)
#pragma unroll
            for (int n = 0; n < 4; ++n) {
                acc[m][n] = __builtin_amdgcn_mfma_f32_16x16x32_bf16(a0[m], b0[n], acc[m][n], 0, 0, 0);
                acc[m][n] = __builtin_amdgcn_mfma_f32_16x16x32_bf16(a0[m], b1[n], acc[m][n], 0, 0, 0);
                acc[m][n] = __builtin_amdgcn_mfma_f32_16x16x32_bf16(a1[m], b0[n], acc[m][n], 0, 0, 0);
                acc[m][n] = __builtin_amdgcn_mfma_f32_16x16x32_bf16(a1[m], b1[n], acc[m][n], 0, 0, 0);
            }
    };

    stage(0, 0);
    __syncthreads();
    for (int t = 0; t < NT; ++t) {
        const int cur = t & 1;
        if (t + 1 < NT) stage(t + 1, cur ^ 1);
        compute(cur);
        __syncthreads();
    }

    // epilogue (C/D layout: col=lane&15, row=(lane>>4)*4+reg)
    float bv[4];
    int   cv[4];
#pragma unroll
    for (int n = 0; n < 4; ++n) {
        cv[n] = col0 + wc * 64 + n * 16 + (lane & 15);
        bv[n] = (cv[n] < BDIM) ? bias[cv[n]] : 0.0f;
    }
#pragma unroll
    for (int m = 0; m < 4; ++m) {
        const int gr0 = row0 + wr * 64 + m * 16 + ((lane >> 4) << 2);
#pragma unroll
        for (int r = 0; r < 4; ++r) {
            const int gr = gr0 + r;
            float s2 = 0.0f;
#pragma unroll
            for (int n = 0; n < 4; ++n) {
                if (cv[n] < BDIM) {
                    const float z = acc[m][n][r] + bv[n];
                    Z[(size_t)gr * BDIM + cv[n]] = z;
                    zh[(size_t)gr * KP + cv[n]] = bf16h(z);
                    s2 = __builtin_fmaf(z, z, s2);
                } else if (cv[n] < KP) {
                    zh[(size_t)gr * KP + cv[n]] = 0;   // K-pad columns
                }
            }
            s2 += __shfl_xor(s2, 1);
            s2 += __shfl_xor(s2, 2);
            s2 += __shfl_xor(s2, 4);
            s2 += __shfl_xor(s2, 8);
            if ((lane & 15) == 0) atomicAdd(&zsq[gr], s2);
        }
    }
}

// ---------------------------------------------------------------------------
// GEMM2 (single-plane bf16): dist[m,n] = zsq[m] - 2*(zh.eh) + esq[n]
// BM=128 x BN=64, BK=32 (85 steps), 24KB LDS, 4 blk/CU (16 waves) for TLP.
// dist error sigma ~0.17 -> DELTA=3.0 candidate window + exact fp32 refine.
// ---------------------------------------------------------------------------
__global__ __launch_bounds__(256, 4)
void gemm2_mfma(const unsigned short* __restrict__ Ah, const unsigned short* __restrict__ Bh,
                const float* __restrict__ zsq, const float* __restrict__ esq,
                float* __restrict__ dist)
{
    constexpr int NT = KP / 32;   // 85
    // per buffer: A [128][32] at 0, B [64][32] at 4096 (ushort units)
    __shared__ unsigned short lds[2][6144];

    const int tid  = threadIdx.x;
    const int wid  = tid >> 6;
    const int lane = tid & 63;
    // row-pinned XCD swizzle: grid 1024 = 8 XCD * (8 rowblk * 16 colblk)
    const int bid  = blockIdx.x;
    const int xcd  = bid & 7;
    const int q    = bid >> 3;                // 0..127
    const int row0 = (xcd * 8 + (q >> 4)) << 7;
    const int col0 = (q & 15) << 6;
    const int wr = wid >> 1, wc = wid & 1;

    f32x4 acc[4][2];
#pragma unroll
    for (int m = 0; m < 4; ++m)
#pragma unroll
        for (int n = 0; n < 2; ++n) acc[m][n] = (f32x4)0.0f;

    auto stage = [&](int t, int b) {
        const int kt = t * 32;
        // A tile: 128 rows, 8 chunks
#pragma unroll
        for (int qq = 0; qq < 2; ++qq) {
            const int chunk = wid * 2 + qq;
            const int r     = chunk * 16 + (lane >> 2);
            const int unswz = ((lane & 3) << 4) ^ (((r >> 1) & 3) << 4);
            const unsigned short* g = Ah + (size_t)(row0 + r) * KP + kt + (unswz >> 1);
            __builtin_amdgcn_global_load_lds(
                (const __attribute__((address_space(1))) void*)g,
                (__attribute__((address_space(3))) void*)(&lds[b][chunk * 512]),
                16, 0, 0);
        }
        // B tile: 64 rows, 4 chunks (one per wave)
        {
            const int chunk = wid;
            const int r     = chunk * 16 + (lane >> 2);
            const int unswz = ((lane & 3) << 4) ^ (((r >> 1) & 3) << 4);
            const unsigned short* g = Bh + (size_t)(col0 + r) * KP + kt + (unswz >> 1);
            __builtin_amdgcn_global_load_lds(
                (const __attribute__((address_space(1))) void*)g,
                (__attribute__((address_space(3))) void*)(&lds[b][4096 + chunk * 512]),
                16, 0, 0);
        }
    };

    auto compute = [&](int b) {
        bf16x8 ah[4], bh[2];
        const int kb = (lane >> 4) << 4;
#pragma unroll
        for (int m = 0; m < 4; ++m) {
            const int r   = wr * 64 + m * 16 + (lane & 15);
            const int off = r * 32 + ((kb ^ (((r >> 1) & 3) << 4)) >> 1);
            ah[m] = *reinterpret_cast<const bf16x8*>(&lds[b][off]);
        }
#pragma unroll
        for (int n = 0; n < 2; ++n) {
            const int r   = wc * 32 + n * 16 + (lane & 15);
            const int off = r * 32 + ((kb ^ (((r >> 1) & 3) << 4)) >> 1);
            bh[n] = *reinterpret_cast<const bf16x8*>(&lds[b][4096 + off]);
        }
#pragma unroll
        for (int m = 0; m < 4; ++m)
#pragma unroll
            for (int n = 0; n < 2; ++n)
                acc[m][n] = __builtin_amdgcn_mfma_f32_16x16x32_bf16(ah[m], bh[n], acc[m][n], 0, 0, 0);
    };

    stage(0, 0);
    __syncthreads();
    for (int t = 0; t < NT; ++t) {
        const int cur = t & 1;
        if (t + 1 < NT) stage(t + 1, cur ^ 1);
        compute(cur);
        __syncthreads();
    }

#pragma unroll
    for (int m = 0; m < 4; ++m) {
        const int gr0 = row0 + wr * 64 + m * 16 + ((lane >> 4) << 2);
#pragma unroll
        for (int n = 0; n < 2; ++n) {
            const int gc = col0 + wc * 32 + n * 16 + (lane & 15);
            const float eq = esq[gc];
#pragma unroll
            for (int r = 0; r < 4; ++r) {
                const int gr = gr0 + r;
                dist[(size_t)gr * NCODES + gc] = zsq[gr] - 2.0f * acc[m][n][r] + eq;
            }
        }
    }
}

// ---------------------------------------------------------------------------
// 32 rows per block: two-smallest argmin, softmax, prob/sse accumulation,
// candidate append for ambiguous rows (gap < DELTA).
// ---------------------------------------------------------------------------
static constexpr float DELTA = 3.0f;

__global__ __launch_bounds__(256)
void row_softmax32(const float* __restrict__ dist, float* __restrict__ prob_acc,
                   float* __restrict__ sse, float* __restrict__ out_idx_f,
                   int* __restrict__ out_idx_i, float* __restrict__ gap_out,
                   unsigned* __restrict__ cand, int* __restrict__ cand_count,
                   unsigned long long* __restrict__ row_best)
{
    const int tid = threadIdx.x;
    __shared__ unsigned long long wm0[4], wm1[4];
    __shared__ float wred[4];
    float pacc[4] = {0.f, 0.f, 0.f, 0.f};
    float sse_loc = 0.f;

    for (int rr = 0; rr < 32; ++rr) {
        const int row = blockIdx.x * 32 + rr;
        const float4 d4 = reinterpret_cast<const float4*>(dist + (size_t)row * NCODES)[tid];
        const float dv[4] = {d4.x, d4.y, d4.z, d4.w};

        unsigned long long b0 = 0xFFFFFFFFFFFFFFFFull, b1 = 0xFFFFFFFFFFFFFFFFull;
#pragma unroll
        for (int j = 0; j < 4; ++j) {
            const unsigned long long k = pack_key(dv[j], tid * 4 + j);
            if (k < b0) { b1 = b0; b0 = k; } else if (k < b1) { b1 = k; }
        }
        for (int off = 1; off < 64; off <<= 1) {
            const unsigned long long o0 = __shfl_xor(b0, off);
            const unsigned long long o1 = __shfl_xor(b1, off);
            const unsigned long long nb0 = (b0 < o0) ? b0 : o0;
            const unsigned long long mx  = (b0 < o0) ? o0 : b0;
            const unsigned long long mn1 = (b1 < o1) ? b1 : o1;
            b0 = nb0;
            b1 = (mx < mn1) ? mx : mn1;
        }
        __syncthreads();                       // protect reuse of wm/wred
        if ((tid & 63) == 0) { wm0[tid >> 6] = b0; wm1[tid >> 6] = b1; }
        __syncthreads();
        unsigned long long B0 = wm0[0], B1 = wm1[0];
#pragma unroll
        for (int w = 1; w < 4; ++w) {
            const unsigned long long o0 = wm0[w], o1 = wm1[w];
            const unsigned long long nb0 = (B0 < o0) ? B0 : o0;
            const unsigned long long mx  = (B0 < o0) ? o0 : B0;
            const unsigned long long mn1 = (B1 < o1) ? B1 : o1;
            B0 = nb0;
            B1 = (mx < mn1) ? mx : mn1;
        }
        const float m   = unpack_val(B0);
        const int   idx = (int)(B0 & 0xffffffffu);
        const float gap = unpack_val(B1) - m;

        if (gap < DELTA) {
            if (tid == 0) row_best[row] = 0xFFFFFFFFFFFFFFFFull;
#pragma unroll
            for (int j = 0; j < 4; ++j) {
                if (dv[j] - m < DELTA) {
                    const int slot = atomicAdd(cand_count, 1);
                    if (slot < MAX_CAND)
                        cand[slot] = ((unsigned)row << 10) | (unsigned)(tid * 4 + j);
                }
            }
        }

        float e[4];
        float s_local = 0.0f;
#pragma unroll
        for (int j = 0; j < 4; ++j) { e[j] = expf(m - dv[j]); s_local += e[j]; }
        for (int off = 32; off; off >>= 1) s_local += __shfl_down(s_local, off);
        if ((tid & 63) == 0) wred[tid >> 6] = s_local;
        __syncthreads();
        const float S = wred[0] + wred[1] + wred[2] + wred[3];
        const float inv = 1.0f / S;
#pragma unroll
        for (int j = 0; j < 4; ++j) pacc[j] += e[j] * inv;

        if (tid == 0) {
            out_idx_f[row] = (float)idx;
            out_idx_i[row] = idx;
            gap_out[row]   = gap;
            sse_loc += m;
        }
    }

    const float scale = 0.0001220703125f;      // 1/8192
#pragma unroll
    for (int j = 0; j < 4; ++j)
        if (pacc[j] > 0.0f) atomicAdd(&prob_acc[tid * 4 + j], pacc[j] * scale);
    if (tid == 0) atomicAdd(sse, sse_loc);
}

// ---------------------------------------------------------------------------
// Exact fp32 dist per candidate (one wave per (row,code) pair)
// ---------------------------------------------------------------------------
__global__ __launch_bounds__(256)
void refine2(const float* __restrict__ Zf, const float* __restrict__ emb,
             const unsigned* __restrict__ cand, const int* __restrict__ cand_count,
             const float* __restrict__ zsq, const float* __restrict__ esq,
             unsigned long long* __restrict__ row_best)
{
    const int nwaves = gridDim.x * 4;
    const int wglob  = blockIdx.x * 4 + (threadIdx.x >> 6);
    const int lane   = threadIdx.x & 63;
    const int n = min(*cand_count, MAX_CAND);
    for (int e = wglob; e < n; e += nwaves) {
        const unsigned pc  = cand[e];
        const int row  = (int)(pc >> 10);
        const int code = (int)(pc & 1023u);
        const float4* zp = reinterpret_cast<const float4*>(Zf + (size_t)row * BDIM);
        const float4* ep = reinterpret_cast<const float4*>(emb + (size_t)code * BDIM);
        float a0 = 0, a1 = 0, a2 = 0, a3 = 0;
        for (int k = lane; k < BDIM / 4; k += 64) {
            const float4 z4 = zp[k];
            const float4 e4 = ep[k];
            a0 = __builtin_fmaf(z4.x, e4.x, a0);
            a1 = __builtin_fmaf(z4.y, e4.y, a1);
            a2 = __builtin_fmaf(z4.z, e4.z, a2);
            a3 = __builtin_fmaf(z4.w, e4.w, a3);
        }
        float t = (a0 + a1) + (a2 + a3);
        for (int off = 32; off; off >>= 1) t += __shfl_down(t, off);
        if (lane == 0) {
            const float d = zsq[row] - 2.0f * t + esq[code];
            atomicMin(&row_best[row], pack_key(d, code));
        }
    }
}

// ---------------------------------------------------------------------------
// gather + fixup fused: refine ambiguous rows' index, then q_st = embed[idx]
// ---------------------------------------------------------------------------
__global__ __launch_bounds__(256)
void gather_fix(const float* __restrict__ embed, const float* __restrict__ gap,
                const unsigned long long* __restrict__ row_best,
                int* __restrict__ idxi, float* __restrict__ idxf,
                float* __restrict__ q)
{
    const int row = blockIdx.x;
    __shared__ int code_s;
    if (threadIdx.x == 0) {
        int code = idxi[row];
        if (gap[row] < DELTA) {
            const unsigned long long k = row_best[row];
            if (k != 0xFFFFFFFFFFFFFFFFull) {
                code = (int)(k & 0xffffffffu);
                idxi[row] = code;
                idxf[row] = (float)code;
            }
        }
        code_s = code;
    }
    __syncthreads();
    const int code = code_s;
    const float4* s = reinterpret_cast<const float4*>(embed + (size_t)code * BDIM);
    float4*       d = reinterpret_cast<float4*>(q + (size_t)row * BDIM);
    for (int i = threadIdx.x; i < (BDIM >> 2); i += 256) d[i] = s[i];
}

__global__ __launch_bounds__(256)
void finalize(const float* __restrict__ prob_acc, const float* __restrict__ sse,
              float* __restrict__ out)
{
    const int tid = threadIdx.x;
    float ent = 0.0f;
    for (int c = tid; c < NCODES; c += 256) {
        const float a = prob_acc[c];
        ent -= a * logf(a + 1e-8f);
    }
    for (int off = 32; off; off >>= 1) ent += __shfl_down(ent, off);
    __shared__ float wred[4];
    if ((tid & 63) == 0) wred[tid >> 6] = ent;
    __syncthreads();
    if (tid == 0) {
        out[QST_N + M_ROWS + 0] = sse[0] / 22118400.0f;
        out[QST_N + M_ROWS + 1] = wred[0] + wred[1] + wred[2] + wred[3];
    }
}

extern "C" void kernel_launch(void* const* d_in, const int* in_sizes, int n_in,
                              void* d_out, int out_size, void* d_ws, size_t ws_size,
                              hipStream_t stream)
{
    (void)in_sizes; (void)n_in; (void)out_size; (void)ws_size;
    const float* slot = (const float*)d_in[0];
    const float* W    = (const float*)d_in[1];
    const float* bpr  = (const float*)d_in[2];
    const float* emb  = (const float*)d_in[3];

    float* out  = (float*)d_out;
    float* Z    = out;              // z_e lives in the q_st region until gather
    float* idxf = out + QST_N;

    // ---- workspace layout (~84 MB; ws proven >= 129 MB in rounds 3-7) ----
    const size_t DIST_B = (size_t)M_ROWS * NCODES * 4;          // 33,554,432
    const size_t ZH_B   = (size_t)M_ROWS * KP * 2;              // 44,564,480
    const size_t EH_B   = (size_t)NCODES * KP * 2;              //  5,570,560

    char* w = (char*)d_ws;
    float* dist = (float*)w;                          w += DIST_B;
    // slot/W split-2 planes alias the dist region (dead before gemm2 writes it)
    unsigned short* sh2 = (unsigned short*)dist;
    unsigned short* sl2 = sh2 + (size_t)M_ROWS * DMODEL;
    unsigned short* wh2 = sl2 + (size_t)M_ROWS * DMODEL;
    unsigned short* wm2 = wh2 + (size_t)NPAD * DMODEL;

    unsigned short* zh = (unsigned short*)w;          w += ZH_B;
    unsigned short* eh = (unsigned short*)w;          w += EH_B;
    float* zsq  = (float*)w;                          w += (size_t)M_ROWS * 4;
    float* esq  = (float*)w;                          w += (size_t)NCODES * 4;
    float* gap  = (float*)w;                          w += (size_t)M_ROWS * 4;
    int*   idxi = (int*)w;                            w += (size_t)M_ROWS * 4;
    float* prob = (float*)w;                          w += (size_t)NCODES * 4;
    float* sse  = (float*)w;                          w += 256;
    unsigned long long* rbest = (unsigned long long*)w; w += (size_t)M_ROWS * 8;
    unsigned* cand = (unsigned*)w;                    w += (size_t)MAX_CAND * 4;
    int* ccount = (int*)w;

    // fused prep: 1024 embed blocks + 704 W blocks + 2048 slot blocks
    prep<<<NCODES + NPAD / 4 + (M_ROWS * DMODEL / 4) / 256, 256, 0, stream>>>(
        emb, W, slot, eh, esq, wh2, wm2, sh2, sl2, prob, sse, ccount, zsq);
    gemm1_mfma<<<(NPAD / 128) * (M_ROWS / 128), 256, 0, stream>>>(
        sh2, sl2, wh2, wm2, bpr, Z, zh, zsq);
    gemm2_mfma<<<(NCODES / 64) * (M_ROWS / 128), 256, 0, stream>>>(
        zh, eh, zsq, esq, dist);
    row_softmax32<<<M_ROWS / 32, 256, 0, stream>>>(dist, prob, sse, idxf, idxi, gap,
                                                   cand, ccount, rbest);
    refine2<<<256, 256, 0, stream>>>(Z, emb, cand, ccount, zsq, esq, rbest);
    gather_fix<<<M_ROWS, 256, 0, stream>>>(emb, gap, rbest, idxi, idxf, Z);
    finalize<<<1, 256, 0, stream>>>(prob, sse, out);
}